// Round 9
// baseline (188.732 us; speedup 1.0000x reference)
//
#include <hip/hip_runtime.h>

typedef float f32x2 __attribute__((ext_vector_type(2)));
typedef float f32x4 __attribute__((ext_vector_type(4)));
typedef float f32x16 __attribute__((ext_vector_type(16)));
typedef short bf16x8 __attribute__((ext_vector_type(8)));
typedef unsigned u32x2 __attribute__((ext_vector_type(2)));
typedef unsigned short u16;

#define S_LEN 4096
#define DMODEL 1024
#define NH 16
#define DK 64

// 1/sqrt(64) * log2(e): softmax runs in base-2 domain
#define SCALE_Q 0.18033688f

static __device__ __forceinline__ u16 f2bf(float x) {
  union { float f; unsigned u; } v; v.f = x;
  unsigned r = v.u + 0x7fffu + ((v.u >> 16) & 1u);  // RNE
  return (u16)(r >> 16);
}

static __device__ __forceinline__ float bf2f(u16 x) {
  union { unsigned u; float f; } v; v.u = ((unsigned)x) << 16;
  return v.f;
}

#if __has_builtin(__builtin_amdgcn_exp2f)
#define EXP2F __builtin_amdgcn_exp2f
#else
#define EXP2F exp2f
#endif

static __device__ __forceinline__ unsigned pkbf(float lo, float hi) {
  unsigned r;
  asm("v_cvt_pk_bf16_f32 %0, %1, %2" : "=v"(r) : "v"(lo), "v"(hi));
  return r;
}

static __device__ __forceinline__ void plswap(unsigned& a, unsigned& b, int hi) {
#if __has_builtin(__builtin_amdgcn_permlane32_swap)
  u32x2 r = __builtin_amdgcn_permlane32_swap(a, b, false, false);
  a = r.x; b = r.y;
  (void)hi;
#else
  unsigned ax = __shfl_xor(a, 32), bx = __shfl_xor(b, 32);
  unsigned na = hi ? bx : a;
  unsigned nb = hi ? b : ax;
  a = na; b = nb;
#endif
}

static __device__ __forceinline__ void gload16(const void* g, void* l) {
  void* gg = (void*)g;
  __builtin_amdgcn_global_load_lds(
      (__attribute__((address_space(1))) void*)gg,
      (__attribute__((address_space(3))) void*)l, 16, 0, 0);
}

// ---------------------------------------------------------------------------
// 4x W (K,N) f32 -> Wt (N,K) bf16, one launch (blockIdx.z selects weight)
// ---------------------------------------------------------------------------
__global__ __launch_bounds__(256) void wcast4(const float* __restrict__ W0,
                                              const float* __restrict__ W1,
                                              const float* __restrict__ W2,
                                              const float* __restrict__ W3,
                                              u16* __restrict__ Wt) {
  __shared__ float t[32][33];
  const int z = blockIdx.z;
  const float* W = (z == 0) ? W0 : (z == 1) ? W1 : (z == 2) ? W2 : W3;
  u16* dst = Wt + (size_t)z * DMODEL * DMODEL;
  const int x = threadIdx.x, y = threadIdx.y;
  const int n0 = blockIdx.x * 32, k0 = blockIdx.y * 32;
#pragma unroll
  for (int i = 0; i < 4; ++i)
    t[y + 8 * i][x] = W[(size_t)(k0 + y + 8 * i) * DMODEL + n0 + x];
  __syncthreads();
#pragma unroll
  for (int i = 0; i < 4; ++i)
    dst[(size_t)(n0 + y + 8 * i) * DMODEL + k0 + x] = f2bf(t[x][y + 8 * i]);
}

// ---------------------------------------------------------------------------
// 3x f32 -> bf16 elementwise, one launch (blockIdx.x>>10 selects source)
// ---------------------------------------------------------------------------
__global__ __launch_bounds__(256) void castbf3(const float* __restrict__ A,
                                               const float* __restrict__ B,
                                               const float* __restrict__ C,
                                               u16* __restrict__ out) {
  const int z = blockIdx.x >> 10;
  const int b = blockIdx.x & 1023;
  const float* src = (z == 0) ? A : (z == 1) ? B : C;
  u16* dst = out + (size_t)z * S_LEN * DMODEL;
  const int n8 = S_LEN * DMODEL / 8;
  for (int i = b * 256 + threadIdx.x; i < n8; i += 1024 * 256) {
    float4 a = ((const float4*)src)[2 * i];
    float4 c = ((const float4*)src)[2 * i + 1];
    union { ushort4 u[2]; int4 q; } t;
    t.u[0].x = f2bf(a.x); t.u[0].y = f2bf(a.y);
    t.u[0].z = f2bf(a.z); t.u[0].w = f2bf(a.w);
    t.u[1].x = f2bf(c.x); t.u[1].y = f2bf(c.y);
    t.u[1].z = f2bf(c.z); t.u[1].w = f2bf(c.w);
    ((int4*)dst)[i] = t.q;
  }
}

// ---------------------------------------------------------------------------
// pgemm: C(4096,1024) = A(4096,1024)bf16 @ Wt^T + bias, m97 128x128 tile.
// ---------------------------------------------------------------------------
template <int MODE>
__global__ __launch_bounds__(256) void pgemm(const u16* __restrict__ Abase,
                                             const u16* __restrict__ Btbase,
                                             const float* __restrict__ bq,
                                             const float* __restrict__ bk,
                                             const float* __restrict__ bv,
                                             void* __restrict__ outbase) {
  __shared__ __align__(16) char Al[16384];   // [128][128B] linear, XOR-swizzled
  __shared__ __align__(16) char Bl[16384];
  const int nblk = gridDim.x, cpx = nblk >> 3;
  const int b0 = blockIdx.x;
  const int bid = (b0 & 7) * cpx + (b0 >> 3);   // XCD swizzle (nblk%8==0)
  const int z = (MODE == 0) ? (bid >> 8) : 0;
  const int rem = bid & 255;
  const int nb = rem & 7, mb = rem >> 3;
  const int m0 = mb * 128, n0 = nb * 128;
  const int tid = threadIdx.x, lane = tid & 63, wid = tid >> 6;
  const int gq = lane >> 4, c16 = lane & 15;
  const int wm = (wid >> 1) * 64, wn = (wid & 1) * 64;
  const char* Ab = (const char*)(Abase + (size_t)z * S_LEN * DMODEL);
  const char* Bb = (const char*)(Btbase + (size_t)z * DMODEL * DMODEL);
  const float* bias = (z == 0) ? bq : (z == 1 ? bk : bv);
  const float scale = (MODE == 0 && z == 0) ? SCALE_Q : 1.0f;

  f32x4 acc[4][4] = {};

  for (int kt = 0; kt < 16; ++kt) {
    const int kb = kt * 128;
#pragma unroll
    for (int p = 0; p < 4; ++p) {
      int lin = p * 4096 + tid * 16;
      int row = lin >> 7;
      int colg = (lin & 127) ^ ((row & 7) << 4);
      gload16(Ab + (size_t)(m0 + row) * 2048 + kb + colg,
              Al + p * 4096 + wid * 1024);
    }
#pragma unroll
    for (int p = 0; p < 4; ++p) {
      int lin = p * 4096 + tid * 16;
      int row = lin >> 7;
      int colg = (lin & 127) ^ ((row & 7) << 4);
      gload16(Bb + (size_t)(n0 + row) * 2048 + kb + colg,
              Bl + p * 4096 + wid * 1024);
    }
    __syncthreads();
#pragma unroll
    for (int kk = 0; kk < 2; ++kk) {
      bf16x8 a[4], b[4];
#pragma unroll
      for (int m = 0; m < 4; ++m) {
        int row = wm + m * 16 + c16;
        a[m] = *(const bf16x8*)(Al + row * 128 +
                                ((kk * 64 + gq * 16) ^ ((row & 7) << 4)));
      }
#pragma unroll
      for (int n = 0; n < 4; ++n) {
        int row = wn + n * 16 + c16;
        b[n] = *(const bf16x8*)(Bl + row * 128 +
                                ((kk * 64 + gq * 16) ^ ((row & 7) << 4)));
      }
#pragma unroll
      for (int m = 0; m < 4; ++m)
#pragma unroll
        for (int n = 0; n < 4; ++n)
          acc[m][n] =
              __builtin_amdgcn_mfma_f32_16x16x32_bf16(a[m], b[n], acc[m][n], 0, 0, 0);
    }
    __syncthreads();
  }

#pragma unroll
  for (int m = 0; m < 4; ++m) {
#pragma unroll
    for (int n = 0; n < 4; ++n) {
      const int row = m0 + wm + m * 16 + gq * 4;
      const int col = n0 + wn + n * 16 + c16;
      const float bb = bias[col];
      if (MODE == 1) {
        float* of = (float*)outbase;
#pragma unroll
        for (int j = 0; j < 4; ++j)
          of[(size_t)(row + j) * DMODEL + col] = acc[m][n][j] + bb;
      } else if (z == 2) {
        // V: (H,64,S) transposed; 4 consecutive s -> one 8B store
        u16* ov = (u16*)outbase + (size_t)2 * S_LEN * DMODEL;
        ushort4 u;
        u.x = f2bf(acc[m][n][0] + bb);
        u.y = f2bf(acc[m][n][1] + bb);
        u.z = f2bf(acc[m][n][2] + bb);
        u.w = f2bf(acc[m][n][3] + bb);
        *(ushort4*)(ov + ((size_t)(col >> 6) * DK + (col & 63)) * S_LEN + row) = u;
      } else {
        u16* oq = (u16*)outbase + (size_t)z * S_LEN * DMODEL;
#pragma unroll
        for (int j = 0; j < 4; ++j)
          oq[((size_t)(col >> 6) * S_LEN + row + j) * DK + (col & 63)] =
              f2bf((acc[m][n][j] + bb) * scale);
      }
    }
  }
}

// ---------------------------------------------------------------------------
// Flash attention, swapped-QK^T, fixed-max base-2 softmax, KV-split x2,
// Q-REUSE x2: each wave owns 64 q-rows (2 fragment sets A/B); every K/V
// fragment read from LDS feeds 2 MFMAs -> LDS:MFMA ratio 1:2 (was 1:1).
// 4 waves x 64 q = 256 q-rows/block, grid 512 (16h x 16qblk x 2kv).
// Counted-vmcnt double-barrier per tile (4 staging loads -> vmcnt(4)).
// ---------------------------------------------------------------------------
__global__ __launch_bounds__(256) void attn2(const u16* __restrict__ q,
                                             const u16* __restrict__ k,
                                             const u16* __restrict__ vt,
                                             u16* __restrict__ Opart,
                                             float* __restrict__ Lpart) {
  __shared__ __align__(16) char smem[32768];  // 2 bufs x (K 8KB + V^T 8KB)
  const int bid0 = blockIdx.x;
  const int bid = (bid0 & 7) * 64 + (bid0 >> 3);  // XCD swizzle, 512%8==0
  const int h = bid >> 5;
  const int kvh = (bid >> 4) & 1;
  const int qblk = bid & 15;
  const int tid = threadIdx.x;
  const int wid = tid >> 6, lane = tid & 63;
  const int l31 = lane & 31, hi = lane >> 5;

  const char* kpb = (const char*)k + (size_t)h * S_LEN * (DK * 2);
  const char* vtb = (const char*)vt + (size_t)h * DK * (S_LEN * 2);

  // Q B-fragments, 2 sets: set A = rows q0w+l31, set B = rows q0w+32+l31
  const int q0w = qblk * 256 + wid * 64;
  const u16* qrowA = q + ((size_t)h * S_LEN + q0w + l31) * DK;
  const u16* qrowB = qrowA + 32 * DK;
  bf16x8 qfA[4], qfB[4];
#pragma unroll
  for (int dt = 0; dt < 4; ++dt) {
    qfA[dt] = *(const bf16x8*)(qrowA + dt * 16 + hi * 8);
    qfB[dt] = *(const bf16x8*)(qrowB + dt * 16 + hi * 8);
  }

  f32x16 oA0 = {}, oA1 = {}, oB0 = {}, oB1 = {};  // O^T[d,q] per set
  f32x2 laccA = {0.f, 0.f}, laccB = {0.f, 0.f};

  const int woff = wid << 10;
  const int kt0 = kvh * 32;       // 32 tiles per half
  const int kt1 = kt0 + 32;

  // loop-invariant per-lane ds-read byte offsets (swizzled)
  const int swz = (l31 & 7) << 4;
  int dsa[4];
#pragma unroll
  for (int dt = 0; dt < 4; ++dt)
    dsa[dt] = (l31 << 7) + ((dt * 32 + hi * 16) ^ swz);

  // induction global staging pointers (2 K-loads + 2 V-loads per thread)
  const int lin0 = tid * 16, lin1 = 4096 + tid * 16;
  const int sw0 = lin0 ^ (((lin0 >> 7) & 7) << 4);
  const int sw1 = lin1 ^ (((lin1 >> 7) & 7) << 4);
  const char* gk0 = kpb + (size_t)kt0 * 8192 + sw0;
  const char* gk1 = kpb + (size_t)kt0 * 8192 + sw1;
  const char* gv0 = vtb + (size_t)(lin0 >> 7) * 8192 + (size_t)kt0 * 128 + (sw0 & 127);
  const char* gv1 = vtb + (size_t)(lin1 >> 7) * 8192 + (size_t)kt0 * 128 + (sw1 & 127);

  // prologue: stage tile kt0 into buf0
  gload16(gk0, smem + woff);          gk0 += 8192;
  gload16(gk1, smem + 4096 + woff);   gk1 += 8192;
  gload16(gv0, smem + 8192 + woff);   gv0 += 128;
  gload16(gv1, smem + 12288 + woff);  gv1 += 128;

  auto body = [&](const int CUR, const int NXT, bool doStage) {
    if (doStage) {
      gload16(gk0, smem + NXT + woff);          gk0 += 8192;
      gload16(gk1, smem + NXT + 4096 + woff);   gk1 += 8192;
      gload16(gv0, smem + NXT + 8192 + woff);   gv0 += 128;
      gload16(gv1, smem + NXT + 12288 + woff);  gv1 += 128;
      asm volatile("s_waitcnt vmcnt(4)" ::: "memory");  // CUR staged; NXT in flight
    } else {
      asm volatile("s_waitcnt vmcnt(0)" ::: "memory");
    }
    __builtin_amdgcn_s_barrier();   // all waves: CUR data ready

    const char* kb = smem + CUR;
    const char* vb = smem + CUR + 8192;

    // QK^T swapped: st[k,q]; each K fragment feeds both q-sets
    f32x16 stA0 = {}, stA1 = {}, stB0 = {}, stB1 = {};
    __builtin_amdgcn_s_setprio(1);
#pragma unroll
    for (int dt = 0; dt < 4; ++dt) {
      bf16x8 k0 = *(const bf16x8*)(kb + dsa[dt]);
      bf16x8 k1 = *(const bf16x8*)(kb + 4096 + dsa[dt]);
      stA0 = __builtin_amdgcn_mfma_f32_32x32x16_bf16(k0, qfA[dt], stA0, 0, 0, 0);
      stA1 = __builtin_amdgcn_mfma_f32_32x32x16_bf16(k1, qfA[dt], stA1, 0, 0, 0);
      stB0 = __builtin_amdgcn_mfma_f32_32x32x16_bf16(k0, qfB[dt], stB0, 0, 0, 0);
      stB1 = __builtin_amdgcn_mfma_f32_32x32x16_bf16(k1, qfB[dt], stB1, 0, 0, 0);
    }
    __builtin_amdgcn_s_setprio(0);

    union UF { unsigned w[4]; bf16x8 v; };
    UF fA[4], fB[4];

    // set A: fixed-max base-2 softmax fused with bf16 pack
    {
      unsigned w0[8], w1[8];
      f32x2 s2 = {0.f, 0.f};
#pragma unroll
      for (int i = 0; i < 8; ++i) {
        float a0 = EXP2F(stA0[2 * i]), a1 = EXP2F(stA0[2 * i + 1]);
        f32x2 t = {a0, a1}; s2 += t;
        w0[i] = pkbf(a0, a1);
      }
#pragma unroll
      for (int i = 0; i < 8; ++i) {
        float a0 = EXP2F(stA1[2 * i]), a1 = EXP2F(stA1[2 * i + 1]);
        f32x2 t = {a0, a1}; s2 += t;
        w1[i] = pkbf(a0, a1);
      }
      laccA += s2;
#pragma unroll
      for (int g = 0; g < 2; ++g)
#pragma unroll
        for (int j = 0; j < 2; ++j) {
          unsigned a = w0[4 * g + j], b = w0[4 * g + j + 2];
          plswap(a, b, hi);
          fA[g].w[j] = a; fA[g].w[j + 2] = b;
          unsigned c = w1[4 * g + j], d = w1[4 * g + j + 2];
          plswap(c, d, hi);
          fA[2 + g].w[j] = c; fA[2 + g].w[j + 2] = d;
        }
    }
    // set B
    {
      unsigned w0[8], w1[8];
      f32x2 s2 = {0.f, 0.f};
#pragma unroll
      for (int i = 0; i < 8; ++i) {
        float a0 = EXP2F(stB0[2 * i]), a1 = EXP2F(stB0[2 * i + 1]);
        f32x2 t = {a0, a1}; s2 += t;
        w0[i] = pkbf(a0, a1);
      }
#pragma unroll
      for (int i = 0; i < 8; ++i) {
        float a0 = EXP2F(stB1[2 * i]), a1 = EXP2F(stB1[2 * i + 1]);
        f32x2 t = {a0, a1}; s2 += t;
        w1[i] = pkbf(a0, a1);
      }
      laccB += s2;
#pragma unroll
      for (int g = 0; g < 2; ++g)
#pragma unroll
        for (int j = 0; j < 2; ++j) {
          unsigned a = w0[4 * g + j], b = w0[4 * g + j + 2];
          plswap(a, b, hi);
          fB[g].w[j] = a; fB[g].w[j + 2] = b;
          unsigned c = w1[4 * g + j], d = w1[4 * g + j + 2];
          plswap(c, d, hi);
          fB[2 + g].w[j] = c; fB[2 + g].w[j + 2] = d;
        }
    }

    // PV: each V fragment feeds both q-sets
    __builtin_amdgcn_s_setprio(1);
#pragma unroll
    for (int kt2 = 0; kt2 < 4; ++kt2) {
      bf16x8 v0 = *(const bf16x8*)(vb + dsa[kt2]);
      bf16x8 v1 = *(const bf16x8*)(vb + 4096 + dsa[kt2]);
      oA0 = __builtin_amdgcn_mfma_f32_32x32x16_bf16(v0, fA[kt2].v, oA0, 0, 0, 0);
      oA1 = __builtin_amdgcn_mfma_f32_32x32x16_bf16(v1, fA[kt2].v, oA1, 0, 0, 0);
      oB0 = __builtin_amdgcn_mfma_f32_32x32x16_bf16(v0, fB[kt2].v, oB0, 0, 0, 0);
      oB1 = __builtin_amdgcn_mfma_f32_32x32x16_bf16(v1, fB[kt2].v, oB1, 0, 0, 0);
    }
    __builtin_amdgcn_s_setprio(0);

    __builtin_amdgcn_s_barrier();   // all waves done reading CUR
  };

  for (int kt = kt0; kt < kt1; kt += 2) {
    body(0, 16384, kt + 1 < kt1);
    body(16384, 0, kt + 2 < kt1);
  }

  // epilogue: store unnormalized partial O^T (bf16) + partial l (f32), 2 sets
  const float lA = laccA.x + laccA.y;
  const float lrowA = lA + __shfl_xor(lA, 32);
  const float lB = laccB.x + laccB.y;
  const float lrowB = lB + __shfl_xor(lB, 32);
  u16* ObA = Opart + ((((size_t)kvh * NH + h) * S_LEN) + q0w + l31) * DK;
  u16* ObB = ObA + (size_t)32 * DK;
#pragma unroll
  for (int g = 0; g < 4; ++g) {
    ushort4 u;
    u.x = f2bf(oA0[g * 4 + 0]); u.y = f2bf(oA0[g * 4 + 1]);
    u.z = f2bf(oA0[g * 4 + 2]); u.w = f2bf(oA0[g * 4 + 3]);
    *(ushort4*)(ObA + 8 * g + 4 * hi) = u;
    u.x = f2bf(oA1[g * 4 + 0]); u.y = f2bf(oA1[g * 4 + 1]);
    u.z = f2bf(oA1[g * 4 + 2]); u.w = f2bf(oA1[g * 4 + 3]);
    *(ushort4*)(ObA + 32 + 8 * g + 4 * hi) = u;
    u.x = f2bf(oB0[g * 4 + 0]); u.y = f2bf(oB0[g * 4 + 1]);
    u.z = f2bf(oB0[g * 4 + 2]); u.w = f2bf(oB0[g * 4 + 3]);
    *(ushort4*)(ObB + 8 * g + 4 * hi) = u;
    u.x = f2bf(oB1[g * 4 + 0]); u.y = f2bf(oB1[g * 4 + 1]);
    u.z = f2bf(oB1[g * 4 + 2]); u.w = f2bf(oB1[g * 4 + 3]);
    *(ushort4*)(ObB + 32 + 8 * g + 4 * hi) = u;
  }
  Lpart[((size_t)kvh * NH + h) * S_LEN + q0w + l31] = lrowA;
  Lpart[((size_t)kvh * NH + h) * S_LEN + q0w + 32 + l31] = lrowB;
}

// ---------------------------------------------------------------------------
// combine: comb[q][h*64+d] = sum_kv(O_kv) / sum_kv(l_kv), bf16 partials (x2)
// ---------------------------------------------------------------------------
__global__ __launch_bounds__(256) void combine(const u16* __restrict__ Op,
                                               const float* __restrict__ Lp,
                                               u16* __restrict__ comb) {
  const int id = blockIdx.x * 256 + threadIdx.x;   // 1M threads
  const int h = id >> 16;
  const int rem = id & 65535;
  const int qv = rem >> 4;
  const int d4 = (rem & 15) << 2;
  const size_t str = (size_t)NH * S_LEN * DK;
  const size_t base = (((size_t)h * S_LEN) + qv) * DK + d4;
  float o0 = 0.f, o1 = 0.f, o2 = 0.f, o3 = 0.f, l = 0.f;
#pragma unroll
  for (int kv = 0; kv < 2; ++kv) {
    ushort4 u = *(const ushort4*)(Op + kv * str + base);
    o0 += bf2f(u.x); o1 += bf2f(u.y); o2 += bf2f(u.z); o3 += bf2f(u.w);
    l += Lp[(size_t)kv * NH * S_LEN + (size_t)h * S_LEN + qv];
  }
  const float inv = 1.f / l;
  ushort4 u;
  u.x = f2bf(o0 * inv);
  u.y = f2bf(o1 * inv);
  u.z = f2bf(o2 * inv);
  u.w = f2bf(o3 * inv);
  *(ushort4*)(comb + (size_t)qv * DMODEL + h * DK + d4) = u;
}

// ---------------------------------------------------------------------------
extern "C" void kernel_launch(void* const* d_in, const int* in_sizes, int n_in,
                              void* d_out, int out_size, void* d_ws, size_t ws_size,
                              hipStream_t stream) {
  (void)in_sizes; (void)n_in; (void)out_size; (void)ws_size;
  const float* Q   = (const float*)d_in[0];
  const float* K   = (const float*)d_in[1];
  const float* V   = (const float*)d_in[2];
  const float* W_Q = (const float*)d_in[3];
  const float* b_Q = (const float*)d_in[4];
  const float* W_K = (const float*)d_in[5];
  const float* b_K = (const float*)d_in[6];
  const float* W_V = (const float*)d_in[7];
  const float* b_V = (const float*)d_in[8];
  const float* W_O = (const float*)d_in[9];
  const float* b_O = (const float*)d_in[10];
  float* out = (float*)d_out;

  char* ws = (char*)d_ws;
  const size_t MB = 1024 * 1024;
  u16* WtQ = (u16*)ws;                        // 4 x 2MB = [0, 8MB)
  u16* Qbf = (u16*)(ws + 8 * MB);             // 3 x 8MB = [8, 32MB); dead after pgemm<0>
  u16* Opart = (u16*)(ws + 8 * MB);           // 2 x 8MB = [8, 24MB) bf16 (overlays Qbf)
  u16* qp   = (u16*)(ws + 40 * MB);           // (H,S,64)  [40,48)
  u16* kp   = qp + (size_t)S_LEN * DMODEL;    //           [48,56)
  u16* vtp  = kp + (size_t)S_LEN * DMODEL;    // (H,64,S)  [56,64)
  u16* comb = vtp + (size_t)S_LEN * DMODEL;   // (S,1024)  [64,72)
  float* Lpart = (float*)(ws + 72 * MB);      // 2 x (H,S) f32 = 512KB

  dim3 tb(32, 8);
  dim3 tg4(32, 32, 4);
  wcast4<<<tg4, tb, 0, stream>>>(W_Q, W_K, W_V, W_O, WtQ);

  castbf3<<<3072, 256, 0, stream>>>(Q, K, V, Qbf);

  pgemm<0><<<768, 256, 0, stream>>>(Qbf, WtQ, b_Q, b_K, b_V, qp);

  attn2<<<512, 256, 0, stream>>>(qp, kp, vtp, Opart, Lpart);
  combine<<<4096, 256, 0, stream>>>(Opart, Lpart, comb);

  pgemm<1><<<256, 256, 0, stream>>>(comb, WtQ + (size_t)3 * DMODEL * DMODEL,
                                    b_O, b_O, b_O, out);
}

// Round 11
// 171.070 us; speedup vs baseline: 1.1032x; 1.1032x over previous
//
#include <hip/hip_runtime.h>

typedef float f32x2 __attribute__((ext_vector_type(2)));
typedef float f32x4 __attribute__((ext_vector_type(4)));
typedef float f32x16 __attribute__((ext_vector_type(16)));
typedef short bf16x8 __attribute__((ext_vector_type(8)));
typedef unsigned u32x2 __attribute__((ext_vector_type(2)));
typedef unsigned short u16;

#define S_LEN 4096
#define DMODEL 1024
#define NH 16
#define DK 64

// 1/sqrt(64) * log2(e): softmax runs in base-2 domain
#define SCALE_Q 0.18033688f

static __device__ __forceinline__ u16 f2bf(float x) {
  union { float f; unsigned u; } v; v.f = x;
  unsigned r = v.u + 0x7fffu + ((v.u >> 16) & 1u);  // RNE
  return (u16)(r >> 16);
}

static __device__ __forceinline__ float bf2f(u16 x) {
  union { unsigned u; float f; } v; v.u = ((unsigned)x) << 16;
  return v.f;
}

#if __has_builtin(__builtin_amdgcn_exp2f)
#define EXP2F __builtin_amdgcn_exp2f
#else
#define EXP2F exp2f
#endif

static __device__ __forceinline__ unsigned pkbf(float lo, float hi) {
  unsigned r;
  asm("v_cvt_pk_bf16_f32 %0, %1, %2" : "=v"(r) : "v"(lo), "v"(hi));
  return r;
}

static __device__ __forceinline__ void plswap(unsigned& a, unsigned& b, int hi) {
#if __has_builtin(__builtin_amdgcn_permlane32_swap)
  u32x2 r = __builtin_amdgcn_permlane32_swap(a, b, false, false);
  a = r.x; b = r.y;
  (void)hi;
#else
  unsigned ax = __shfl_xor(a, 32), bx = __shfl_xor(b, 32);
  unsigned na = hi ? bx : a;
  unsigned nb = hi ? b : ax;
  a = na; b = nb;
#endif
}

static __device__ __forceinline__ void gload16(const void* g, void* l) {
  void* gg = (void*)g;
  __builtin_amdgcn_global_load_lds(
      (__attribute__((address_space(1))) void*)gg,
      (__attribute__((address_space(3))) void*)l, 16, 0, 0);
}

// ---------------------------------------------------------------------------
// 4x W (K,N) f32 -> Wt (N,K) bf16, one launch (blockIdx.z selects weight)
// ---------------------------------------------------------------------------
__global__ __launch_bounds__(256) void wcast4(const float* __restrict__ W0,
                                              const float* __restrict__ W1,
                                              const float* __restrict__ W2,
                                              const float* __restrict__ W3,
                                              u16* __restrict__ Wt) {
  __shared__ float t[32][33];
  const int z = blockIdx.z;
  const float* W = (z == 0) ? W0 : (z == 1) ? W1 : (z == 2) ? W2 : W3;
  u16* dst = Wt + (size_t)z * DMODEL * DMODEL;
  const int x = threadIdx.x, y = threadIdx.y;
  const int n0 = blockIdx.x * 32, k0 = blockIdx.y * 32;
#pragma unroll
  for (int i = 0; i < 4; ++i)
    t[y + 8 * i][x] = W[(size_t)(k0 + y + 8 * i) * DMODEL + n0 + x];
  __syncthreads();
#pragma unroll
  for (int i = 0; i < 4; ++i)
    dst[(size_t)(n0 + y + 8 * i) * DMODEL + k0 + x] = f2bf(t[x][y + 8 * i]);
}

// ---------------------------------------------------------------------------
// 3x f32 -> bf16 elementwise, one launch (blockIdx.x>>10 selects source)
// ---------------------------------------------------------------------------
__global__ __launch_bounds__(256) void castbf3(const float* __restrict__ A,
                                               const float* __restrict__ B,
                                               const float* __restrict__ C,
                                               u16* __restrict__ out) {
  const int z = blockIdx.x >> 10;
  const int b = blockIdx.x & 1023;
  const float* src = (z == 0) ? A : (z == 1) ? B : C;
  u16* dst = out + (size_t)z * S_LEN * DMODEL;
  const int n8 = S_LEN * DMODEL / 8;
  for (int i = b * 256 + threadIdx.x; i < n8; i += 1024 * 256) {
    float4 a = ((const float4*)src)[2 * i];
    float4 c = ((const float4*)src)[2 * i + 1];
    union { ushort4 u[2]; int4 q; } t;
    t.u[0].x = f2bf(a.x); t.u[0].y = f2bf(a.y);
    t.u[0].z = f2bf(a.z); t.u[0].w = f2bf(a.w);
    t.u[1].x = f2bf(c.x); t.u[1].y = f2bf(c.y);
    t.u[1].z = f2bf(c.z); t.u[1].w = f2bf(c.w);
    ((int4*)dst)[i] = t.q;
  }
}

// ---------------------------------------------------------------------------
// pgemm: C(4096,1024) = A(4096,1024)bf16 @ Wt^T + bias, m97 128x128 tile.
// ---------------------------------------------------------------------------
template <int MODE>
__global__ __launch_bounds__(256) void pgemm(const u16* __restrict__ Abase,
                                             const u16* __restrict__ Btbase,
                                             const float* __restrict__ bq,
                                             const float* __restrict__ bk,
                                             const float* __restrict__ bv,
                                             void* __restrict__ outbase) {
  __shared__ __align__(16) char Al[16384];   // [128][128B] linear, XOR-swizzled
  __shared__ __align__(16) char Bl[16384];
  const int nblk = gridDim.x, cpx = nblk >> 3;
  const int b0 = blockIdx.x;
  const int bid = (b0 & 7) * cpx + (b0 >> 3);   // XCD swizzle (nblk%8==0)
  const int z = (MODE == 0) ? (bid >> 8) : 0;
  const int rem = bid & 255;
  const int nb = rem & 7, mb = rem >> 3;
  const int m0 = mb * 128, n0 = nb * 128;
  const int tid = threadIdx.x, lane = tid & 63, wid = tid >> 6;
  const int gq = lane >> 4, c16 = lane & 15;
  const int wm = (wid >> 1) * 64, wn = (wid & 1) * 64;
  const char* Ab = (const char*)(Abase + (size_t)z * S_LEN * DMODEL);
  const char* Bb = (const char*)(Btbase + (size_t)z * DMODEL * DMODEL);
  const float* bias = (z == 0) ? bq : (z == 1 ? bk : bv);
  const float scale = (MODE == 0 && z == 0) ? SCALE_Q : 1.0f;

  f32x4 acc[4][4] = {};

  for (int kt = 0; kt < 16; ++kt) {
    const int kb = kt * 128;
#pragma unroll
    for (int p = 0; p < 4; ++p) {
      int lin = p * 4096 + tid * 16;
      int row = lin >> 7;
      int colg = (lin & 127) ^ ((row & 7) << 4);
      gload16(Ab + (size_t)(m0 + row) * 2048 + kb + colg,
              Al + p * 4096 + wid * 1024);
    }
#pragma unroll
    for (int p = 0; p < 4; ++p) {
      int lin = p * 4096 + tid * 16;
      int row = lin >> 7;
      int colg = (lin & 127) ^ ((row & 7) << 4);
      gload16(Bb + (size_t)(n0 + row) * 2048 + kb + colg,
              Bl + p * 4096 + wid * 1024);
    }
    __syncthreads();
#pragma unroll
    for (int kk = 0; kk < 2; ++kk) {
      bf16x8 a[4], b[4];
#pragma unroll
      for (int m = 0; m < 4; ++m) {
        int row = wm + m * 16 + c16;
        a[m] = *(const bf16x8*)(Al + row * 128 +
                                ((kk * 64 + gq * 16) ^ ((row & 7) << 4)));
      }
#pragma unroll
      for (int n = 0; n < 4; ++n) {
        int row = wn + n * 16 + c16;
        b[n] = *(const bf16x8*)(Bl + row * 128 +
                                ((kk * 64 + gq * 16) ^ ((row & 7) << 4)));
      }
#pragma unroll
      for (int m = 0; m < 4; ++m)
#pragma unroll
        for (int n = 0; n < 4; ++n)
          acc[m][n] =
              __builtin_amdgcn_mfma_f32_16x16x32_bf16(a[m], b[n], acc[m][n], 0, 0, 0);
    }
    __syncthreads();
  }

#pragma unroll
  for (int m = 0; m < 4; ++m) {
#pragma unroll
    for (int n = 0; n < 4; ++n) {
      const int row = m0 + wm + m * 16 + gq * 4;
      const int col = n0 + wn + n * 16 + c16;
      const float bb = bias[col];
      if (MODE == 1) {
        float* of = (float*)outbase;
#pragma unroll
        for (int j = 0; j < 4; ++j)
          of[(size_t)(row + j) * DMODEL + col] = acc[m][n][j] + bb;
      } else if (z == 2) {
        // V: (H,64,S) transposed; 4 consecutive s -> one 8B store
        u16* ov = (u16*)outbase + (size_t)2 * S_LEN * DMODEL;
        ushort4 u;
        u.x = f2bf(acc[m][n][0] + bb);
        u.y = f2bf(acc[m][n][1] + bb);
        u.z = f2bf(acc[m][n][2] + bb);
        u.w = f2bf(acc[m][n][3] + bb);
        *(ushort4*)(ov + ((size_t)(col >> 6) * DK + (col & 63)) * S_LEN + row) = u;
      } else {
        u16* oq = (u16*)outbase + (size_t)z * S_LEN * DMODEL;
#pragma unroll
        for (int j = 0; j < 4; ++j)
          oq[((size_t)(col >> 6) * S_LEN + row + j) * DK + (col & 63)] =
              f2bf((acc[m][n][j] + bb) * scale);
      }
    }
  }
}

// ---------------------------------------------------------------------------
// Flash attention, swapped-QK^T, fixed-max base-2 softmax, KV-split x2.
// 512-thread blocks (8 waves x 32 q-rows), grid 512, R8 sync skeleton
// (stage at TOP of body -> counted vmcnt -> barrier -> compute -> barrier)
// with a 4-buffer (64KB) cross-tile pipeline: body t = QK(t) + PV(t-1) as
// one 16-MFMA cluster, then SM(t) into carried fprev. Stage target
// buf[(t+2)&3] was last read at body t-1 (V) -- one full barrier interval
// before the stage; sched_barrier(0) guards against compiler hoisting the
// stage across the preceding s_barrier (R10 failure mode).
// Tile t lives in buf[t&3]: K at +0, V^T at +8192.
// ---------------------------------------------------------------------------
__global__ __launch_bounds__(512, 4) void attn2(const u16* __restrict__ q,
                                                const u16* __restrict__ k,
                                                const u16* __restrict__ vt,
                                                u16* __restrict__ Opart,
                                                float* __restrict__ Lpart) {
  __shared__ __align__(16) char smem[65536];  // 4 bufs x (K 8KB + V^T 8KB)
  const int bid0 = blockIdx.x;
  const int bid = (bid0 & 7) * 64 + (bid0 >> 3);  // XCD swizzle, 512%8==0
  const int h = bid >> 5;
  const int kvh = (bid >> 4) & 1;
  const int qblk = bid & 15;
  const int tid = threadIdx.x;
  const int wid = tid >> 6, lane = tid & 63;
  const int l31 = lane & 31, hi = lane >> 5;

  const char* kpb = (const char*)k + (size_t)h * S_LEN * (DK * 2);
  const char* vtb = (const char*)vt + (size_t)h * DK * (S_LEN * 2);

  // Q B-fragments: col=q=lane&31, kdim d = 16*dt + 8*hi + j
  const int q0w = qblk * 256 + wid * 32;
  const u16* qrow = q + ((size_t)h * S_LEN + q0w + l31) * DK;
  bf16x8 qf[4];
#pragma unroll
  for (int dt = 0; dt < 4; ++dt)
    qf[dt] = *(const bf16x8*)(qrow + dt * 16 + hi * 8);

  f32x16 o0 = {}, o1 = {};   // O^T[d,q]: o0 = d 0..31, o1 = d 32..63
  f32x2 lacc2 = {0.f, 0.f};

  const int woff = wid << 10;     // each wave stages a contiguous 1KB chunk
  const int kt0 = kvh * 32;       // 32 tiles per half

  // loop-invariant per-lane ds-read byte offsets (swizzled), buffer-relative
  const int swz = (l31 & 7) << 4;
  int dsa[4];
#pragma unroll
  for (int dt = 0; dt < 4; ++dt)
    dsa[dt] = (l31 << 7) + ((dt * 32 + hi * 16) ^ swz);

  // induction global staging pointers (1 K-load + 1 V-load per thread/tile)
  const int lin = tid * 16;                       // 0..8176, covers 8KB
  const int sw = lin ^ (((lin >> 7) & 7) << 4);
  const char* gk = kpb + (size_t)kt0 * 8192 + sw;
  const char* gv = vtb + (size_t)(lin >> 7) * 8192 + (size_t)kt0 * 128 + (sw & 127);

  // prologue: stage tile0 -> buf0, tile1 -> buf1
  gload16(gk, smem + woff);                  gk += 8192;
  gload16(gv, smem + 8192 + woff);           gv += 128;
  gload16(gk, smem + 16384 + woff);          gk += 8192;
  gload16(gv, smem + 16384 + 8192 + woff);   gv += 128;

  union UF { unsigned w[4]; bf16x8 v; };
  UF fprev[4];

  // one body's compute: [QK(t) (+ PV(t-1) if dopv)] 16-MFMA cluster, SM(t)
  auto phase = [&](const char* kb, const char* vb, bool dopv) {
    f32x16 st0 = {}, st1 = {};
    __builtin_amdgcn_s_setprio(1);
#pragma unroll
    for (int dt = 0; dt < 4; ++dt) {
      bf16x8 k0 = *(const bf16x8*)(kb + dsa[dt]);
      bf16x8 k1 = *(const bf16x8*)(kb + 4096 + dsa[dt]);
      st0 = __builtin_amdgcn_mfma_f32_32x32x16_bf16(k0, qf[dt], st0, 0, 0, 0);
      st1 = __builtin_amdgcn_mfma_f32_32x32x16_bf16(k1, qf[dt], st1, 0, 0, 0);
      if (dopv) {
        bf16x8 v0 = *(const bf16x8*)(vb + dsa[dt]);
        bf16x8 v1 = *(const bf16x8*)(vb + 4096 + dsa[dt]);
        o0 = __builtin_amdgcn_mfma_f32_32x32x16_bf16(v0, fprev[dt].v, o0, 0, 0, 0);
        o1 = __builtin_amdgcn_mfma_f32_32x32x16_bf16(v1, fprev[dt].v, o1, 0, 0, 0);
      }
    }
    __builtin_amdgcn_s_setprio(0);

    // SM(t): fixed-max base-2 softmax fused with bf16 pack -> fprev
    unsigned w0[8], w1[8];
    f32x2 s2 = {0.f, 0.f};
#pragma unroll
    for (int i = 0; i < 8; ++i) {
      float a0 = EXP2F(st0[2 * i]), a1 = EXP2F(st0[2 * i + 1]);
      f32x2 tt = {a0, a1}; s2 += tt;
      w0[i] = pkbf(a0, a1);
    }
#pragma unroll
    for (int i = 0; i < 8; ++i) {
      float a0 = EXP2F(st1[2 * i]), a1 = EXP2F(st1[2 * i + 1]);
      f32x2 tt = {a0, a1}; s2 += tt;
      w1[i] = pkbf(a0, a1);
    }
    lacc2 += s2;
#pragma unroll
    for (int g = 0; g < 2; ++g)
#pragma unroll
      for (int j = 0; j < 2; ++j) {
        unsigned a = w0[4 * g + j], b = w0[4 * g + j + 2];
        plswap(a, b, hi);
        fprev[g].w[j] = a; fprev[g].w[j + 2] = b;
        unsigned c = w1[4 * g + j], d = w1[4 * g + j + 2];
        plswap(c, d, hi);
        fprev[2 + g].w[j] = c; fprev[2 + g].w[j + 2] = d;
      }
  };

  // ---- body 0: stage tile2 -> buf2; QK(0)+SM(0) only ----
  __builtin_amdgcn_sched_barrier(0);
  gload16(gk, smem + 32768 + woff);         gk += 8192;
  gload16(gv, smem + 32768 + 8192 + woff);  gv += 128;
  asm volatile("s_waitcnt vmcnt(4)" ::: "memory");
  __builtin_amdgcn_s_barrier();
  phase(smem, smem, false);
  __builtin_amdgcn_s_barrier();

  // ---- bodies 1..29: stage tile t+2 -> buf[(t+2)&3] ----
  for (int t = 1; t <= 29; ++t) {
    __builtin_amdgcn_sched_barrier(0);
    const int bs = ((t + 2) & 3) << 14;
    gload16(gk, smem + bs + woff);         gk += 8192;
    gload16(gv, smem + bs + 8192 + woff);  gv += 128;
    asm volatile("s_waitcnt vmcnt(4)" ::: "memory");
    __builtin_amdgcn_s_barrier();
    phase(smem + ((t & 3) << 14), smem + (((t + 3) & 3) << 14) + 8192, true);
    __builtin_amdgcn_s_barrier();
  }

  // ---- body 30 (no stage) ----
  __builtin_amdgcn_sched_barrier(0);
  asm volatile("s_waitcnt vmcnt(2)" ::: "memory");
  __builtin_amdgcn_s_barrier();
  phase(smem + ((30 & 3) << 14), smem + ((29 & 3) << 14) + 8192, true);
  __builtin_amdgcn_s_barrier();

  // ---- body 31 (no stage) ----
  __builtin_amdgcn_sched_barrier(0);
  asm volatile("s_waitcnt vmcnt(0)" ::: "memory");
  __builtin_amdgcn_s_barrier();
  phase(smem + ((31 & 3) << 14), smem + ((30 & 3) << 14) + 8192, true);
  __builtin_amdgcn_s_barrier();

  // ---- epilogue: PV(31) from buf3 (no writes after body 31) ----
  {
    const char* vb = smem + ((31 & 3) << 14) + 8192;
    __builtin_amdgcn_s_setprio(1);
#pragma unroll
    for (int dt = 0; dt < 4; ++dt) {
      bf16x8 v0 = *(const bf16x8*)(vb + dsa[dt]);
      bf16x8 v1 = *(const bf16x8*)(vb + 4096 + dsa[dt]);
      o0 = __builtin_amdgcn_mfma_f32_32x32x16_bf16(v0, fprev[dt].v, o0, 0, 0, 0);
      o1 = __builtin_amdgcn_mfma_f32_32x32x16_bf16(v1, fprev[dt].v, o1, 0, 0, 0);
    }
    __builtin_amdgcn_s_setprio(0);
  }

  // epilogue: store unnormalized partial O^T (bf16) + partial l (f32)
  const float lacc = lacc2.x + lacc2.y;
  const float lrow = lacc + __shfl_xor(lacc, 32);
  u16* Ob = Opart + ((((size_t)kvh * NH + h) * S_LEN) + q0w + l31) * DK;
#pragma unroll
  for (int g = 0; g < 4; ++g) {
    ushort4 u0, u1;
    u0.x = f2bf(o0[g * 4 + 0]); u0.y = f2bf(o0[g * 4 + 1]);
    u0.z = f2bf(o0[g * 4 + 2]); u0.w = f2bf(o0[g * 4 + 3]);
    *(ushort4*)(Ob + 8 * g + 4 * hi) = u0;
    u1.x = f2bf(o1[g * 4 + 0]); u1.y = f2bf(o1[g * 4 + 1]);
    u1.z = f2bf(o1[g * 4 + 2]); u1.w = f2bf(o1[g * 4 + 3]);
    *(ushort4*)(Ob + 32 + 8 * g + 4 * hi) = u1;
  }
  Lpart[((size_t)kvh * NH + h) * S_LEN + q0w + l31] = lrow;
}

// ---------------------------------------------------------------------------
// combine: comb[q][h*64+d] = sum_kv(O_kv) / sum_kv(l_kv), bf16 partials (x2)
// ---------------------------------------------------------------------------
__global__ __launch_bounds__(256) void combine(const u16* __restrict__ Op,
                                               const float* __restrict__ Lp,
                                               u16* __restrict__ comb) {
  const int id = blockIdx.x * 256 + threadIdx.x;   // 1M threads
  const int h = id >> 16;
  const int rem = id & 65535;
  const int qv = rem >> 4;
  const int d4 = (rem & 15) << 2;
  const size_t str = (size_t)NH * S_LEN * DK;
  const size_t base = (((size_t)h * S_LEN) + qv) * DK + d4;
  float o0 = 0.f, o1 = 0.f, o2 = 0.f, o3 = 0.f, l = 0.f;
#pragma unroll
  for (int kv = 0; kv < 2; ++kv) {
    ushort4 u = *(const ushort4*)(Op + kv * str + base);
    o0 += bf2f(u.x); o1 += bf2f(u.y); o2 += bf2f(u.z); o3 += bf2f(u.w);
    l += Lp[(size_t)kv * NH * S_LEN + (size_t)h * S_LEN + qv];
  }
  const float inv = 1.f / l;
  ushort4 u;
  u.x = f2bf(o0 * inv);
  u.y = f2bf(o1 * inv);
  u.z = f2bf(o2 * inv);
  u.w = f2bf(o3 * inv);
  *(ushort4*)(comb + (size_t)qv * DMODEL + h * DK + d4) = u;
}

// ---------------------------------------------------------------------------
extern "C" void kernel_launch(void* const* d_in, const int* in_sizes, int n_in,
                              void* d_out, int out_size, void* d_ws, size_t ws_size,
                              hipStream_t stream) {
  (void)in_sizes; (void)n_in; (void)out_size; (void)ws_size;
  const float* Q   = (const float*)d_in[0];
  const float* K   = (const float*)d_in[1];
  const float* V   = (const float*)d_in[2];
  const float* W_Q = (const float*)d_in[3];
  const float* b_Q = (const float*)d_in[4];
  const float* W_K = (const float*)d_in[5];
  const float* b_K = (const float*)d_in[6];
  const float* W_V = (const float*)d_in[7];
  const float* b_V = (const float*)d_in[8];
  const float* W_O = (const float*)d_in[9];
  const float* b_O = (const float*)d_in[10];
  float* out = (float*)d_out;

  char* ws = (char*)d_ws;
  const size_t MB = 1024 * 1024;
  u16* WtQ = (u16*)ws;                        // 4 x 2MB = [0, 8MB)
  u16* Qbf = (u16*)(ws + 8 * MB);             // 3 x 8MB = [8, 32MB); dead after pgemm<0>
  u16* Opart = (u16*)(ws + 8 * MB);           // 2 x 8MB = [8, 24MB) bf16 (overlays Qbf)
  u16* qp   = (u16*)(ws + 40 * MB);           // (H,S,64)  [40,48)
  u16* kp   = qp + (size_t)S_LEN * DMODEL;    //           [48,56)
  u16* vtp  = kp + (size_t)S_LEN * DMODEL;    // (H,64,S)  [56,64)
  u16* comb = vtp + (size_t)S_LEN * DMODEL;   // (S,1024)  [64,72)
  float* Lpart = (float*)(ws + 72 * MB);      // 2 x (H,S) f32 = 512KB

  dim3 tb(32, 8);
  dim3 tg4(32, 32, 4);
  wcast4<<<tg4, tb, 0, stream>>>(W_Q, W_K, W_V, W_O, WtQ);

  castbf3<<<3072, 256, 0, stream>>>(Q, K, V, Qbf);

  pgemm<0><<<768, 256, 0, stream>>>(Qbf, WtQ, b_Q, b_K, b_V, qp);

  attn2<<<512, 512, 0, stream>>>(qp, kp, vtp, Opart, Lpart);
  combine<<<4096, 256, 0, stream>>>(Opart, Lpart, comb);

  pgemm<1><<<256, 256, 0, stream>>>(comb, WtQ + (size_t)3 * DMODEL * DMODEL,
                                    b_O, b_O, b_O, out);
}

// Round 12
// 164.380 us; speedup vs baseline: 1.1481x; 1.0407x over previous
//
#include <hip/hip_runtime.h>

typedef float f32x2 __attribute__((ext_vector_type(2)));
typedef float f32x4 __attribute__((ext_vector_type(4)));
typedef float f32x16 __attribute__((ext_vector_type(16)));
typedef short bf16x8 __attribute__((ext_vector_type(8)));
typedef unsigned u32x2 __attribute__((ext_vector_type(2)));
typedef unsigned short u16;

#define S_LEN 4096
#define DMODEL 1024
#define NH 16
#define DK 64

// 1/sqrt(64) * log2(e): softmax runs in base-2 domain
#define SCALE_Q 0.18033688f

static __device__ __forceinline__ u16 f2bf(float x) {
  union { float f; unsigned u; } v; v.f = x;
  unsigned r = v.u + 0x7fffu + ((v.u >> 16) & 1u);  // RNE
  return (u16)(r >> 16);
}

static __device__ __forceinline__ float bf2f(u16 x) {
  union { unsigned u; float f; } v; v.u = ((unsigned)x) << 16;
  return v.f;
}

#if __has_builtin(__builtin_amdgcn_exp2f)
#define EXP2F __builtin_amdgcn_exp2f
#else
#define EXP2F exp2f
#endif

static __device__ __forceinline__ unsigned pkbf(float lo, float hi) {
  unsigned r;
  asm("v_cvt_pk_bf16_f32 %0, %1, %2" : "=v"(r) : "v"(lo), "v"(hi));
  return r;
}

static __device__ __forceinline__ void plswap(unsigned& a, unsigned& b, int hi) {
#if __has_builtin(__builtin_amdgcn_permlane32_swap)
  u32x2 r = __builtin_amdgcn_permlane32_swap(a, b, false, false);
  a = r.x; b = r.y;
  (void)hi;
#else
  unsigned ax = __shfl_xor(a, 32), bx = __shfl_xor(b, 32);
  unsigned na = hi ? bx : a;
  unsigned nb = hi ? b : ax;
  a = na; b = nb;
#endif
}

static __device__ __forceinline__ void gload16(const void* g, void* l) {
  void* gg = (void*)g;
  __builtin_amdgcn_global_load_lds(
      (__attribute__((address_space(1))) void*)gg,
      (__attribute__((address_space(3))) void*)l, 16, 0, 0);
}

// ---------------------------------------------------------------------------
// prep: one launch. blocks [0,4096): 4x W (K,N) f32 -> Wt (N,K) bf16 (32x32
// transpose tiles). blocks [4096,7168): 3x f32 -> bf16 elementwise.
// ---------------------------------------------------------------------------
__global__ __launch_bounds__(256) void prep(const float* __restrict__ W0,
                                            const float* __restrict__ W1,
                                            const float* __restrict__ W2,
                                            const float* __restrict__ W3,
                                            u16* __restrict__ Wt,
                                            const float* __restrict__ Q,
                                            const float* __restrict__ K,
                                            const float* __restrict__ V,
                                            u16* __restrict__ Qbf) {
  __shared__ float t[32][33];
  const int b = blockIdx.x;
  const int tid = threadIdx.x;
  if (b < 4096) {
    const int z = b >> 10;
    const int rem = b & 1023;
    const float* W = (z == 0) ? W0 : (z == 1) ? W1 : (z == 2) ? W2 : W3;
    u16* dst = Wt + (size_t)z * DMODEL * DMODEL;
    const int x = tid & 31, y = tid >> 5;          // 32 x 8
    const int n0 = (rem & 31) * 32, k0 = (rem >> 5) * 32;
#pragma unroll
    for (int i = 0; i < 4; ++i)
      t[y + 8 * i][x] = W[(size_t)(k0 + y + 8 * i) * DMODEL + n0 + x];
    __syncthreads();
#pragma unroll
    for (int i = 0; i < 4; ++i)
      dst[(size_t)(n0 + y + 8 * i) * DMODEL + k0 + x] = f2bf(t[x][y + 8 * i]);
  } else {
    const int b2 = b - 4096;
    const int z = b2 >> 10;
    const int blk = b2 & 1023;
    const float* src = (z == 0) ? Q : (z == 1) ? K : V;
    u16* dst = Qbf + (size_t)z * S_LEN * DMODEL;
    const int n8 = S_LEN * DMODEL / 8;
    for (int i = blk * 256 + tid; i < n8; i += 1024 * 256) {
      float4 a = ((const float4*)src)[2 * i];
      float4 c = ((const float4*)src)[2 * i + 1];
      union { ushort4 u[2]; int4 q; } tt;
      tt.u[0].x = f2bf(a.x); tt.u[0].y = f2bf(a.y);
      tt.u[0].z = f2bf(a.z); tt.u[0].w = f2bf(a.w);
      tt.u[1].x = f2bf(c.x); tt.u[1].y = f2bf(c.y);
      tt.u[1].z = f2bf(c.z); tt.u[1].w = f2bf(c.w);
      ((int4*)dst)[i] = tt.q;
    }
  }
}

// ---------------------------------------------------------------------------
// pgemm: C(4096,1024) = A(4096,1024)bf16 @ Wt^T + bias, m97 128x128 tile,
// inner compute on 32x32x16 MFMAs (2x2 outer product per wave; 16 MFMA/kt,
// same LDS bytes as the 16x16 version, faster matrix pipe).
// MODE 0 (grid 768): z = bid>>8 selects Q/K/V; z=0/1 -> head-split bf16
//   (H,S,64) [z=0 scaled]; z=2 -> transposed bf16 (H,64,S).
// MODE 1 (grid 256): f32 flat (S,D) out, bias = bq.
// ---------------------------------------------------------------------------
template <int MODE>
__global__ __launch_bounds__(256) void pgemm(const u16* __restrict__ Abase,
                                             const u16* __restrict__ Btbase,
                                             const float* __restrict__ bq,
                                             const float* __restrict__ bk,
                                             const float* __restrict__ bv,
                                             void* __restrict__ outbase) {
  __shared__ __align__(16) char Al[16384];   // [128][128B] linear, XOR-swizzled
  __shared__ __align__(16) char Bl[16384];
  const int nblk = gridDim.x, cpx = nblk >> 3;
  const int b0 = blockIdx.x;
  const int bid = (b0 & 7) * cpx + (b0 >> 3);   // XCD swizzle (nblk%8==0)
  const int z = (MODE == 0) ? (bid >> 8) : 0;
  const int rem = bid & 255;
  const int nb = rem & 7, mb = rem >> 3;
  const int m0 = mb * 128, n0 = nb * 128;
  const int tid = threadIdx.x, lane = tid & 63, wid = tid >> 6;
  const int l31 = lane & 31, hi = lane >> 5;
  const int wm = (wid >> 1) * 64, wn = (wid & 1) * 64;
  const char* Ab = (const char*)(Abase + (size_t)z * S_LEN * DMODEL);
  const char* Bb = (const char*)(Btbase + (size_t)z * DMODEL * DMODEL);
  const float* bias = (z == 0) ? bq : (z == 1 ? bk : bv);
  const float scale = (MODE == 0 && z == 0) ? SCALE_Q : 1.0f;

  f32x16 acc[2][2] = {};

  for (int kt = 0; kt < 16; ++kt) {
    const int kb = kt * 128;
#pragma unroll
    for (int p = 0; p < 4; ++p) {
      int lin = p * 4096 + tid * 16;
      int row = lin >> 7;
      int colg = (lin & 127) ^ ((row & 7) << 4);
      gload16(Ab + (size_t)(m0 + row) * 2048 + kb + colg,
              Al + p * 4096 + wid * 1024);
    }
#pragma unroll
    for (int p = 0; p < 4; ++p) {
      int lin = p * 4096 + tid * 16;
      int row = lin >> 7;
      int colg = (lin & 127) ^ ((row & 7) << 4);
      gload16(Bb + (size_t)(n0 + row) * 2048 + kb + colg,
              Bl + p * 4096 + wid * 1024);
    }
    __syncthreads();
#pragma unroll
    for (int ks = 0; ks < 4; ++ks) {
      bf16x8 a2[2], b2[2];
#pragma unroll
      for (int f = 0; f < 2; ++f) {
        int row = wm + f * 32 + l31;
        a2[f] = *(const bf16x8*)(Al + row * 128 +
                                 ((ks * 32 + hi * 16) ^ ((row & 7) << 4)));
      }
#pragma unroll
      for (int g = 0; g < 2; ++g) {
        int row = wn + g * 32 + l31;
        b2[g] = *(const bf16x8*)(Bl + row * 128 +
                                 ((ks * 32 + hi * 16) ^ ((row & 7) << 4)));
      }
#pragma unroll
      for (int f = 0; f < 2; ++f)
#pragma unroll
        for (int g = 0; g < 2; ++g)
          acc[f][g] =
              __builtin_amdgcn_mfma_f32_32x32x16_bf16(a2[f], b2[g], acc[f][g], 0, 0, 0);
    }
    __syncthreads();
  }

  // epilogue: 32x32 C/D layout: col = l31, row = (i&3) + 8*(i>>2) + 4*hi
#pragma unroll
  for (int f = 0; f < 2; ++f) {
#pragma unroll
    for (int g = 0; g < 2; ++g) {
      const int col = n0 + wn + g * 32 + l31;
      const int row0 = m0 + wm + f * 32 + 4 * hi;
      const float bb = bias[col];
      if (MODE == 1) {
        float* of = (float*)outbase;
#pragma unroll
        for (int i = 0; i < 16; ++i) {
          const int row = row0 + (i & 3) + 8 * (i >> 2);
          of[(size_t)row * DMODEL + col] = acc[f][g][i] + bb;
        }
      } else if (z == 2) {
        // V: (H,64,S) transposed; 4 consecutive rows (s) -> one 8B store
        u16* ov = (u16*)outbase + (size_t)2 * S_LEN * DMODEL;
        u16* base = ov + ((size_t)(col >> 6) * DK + (col & 63)) * S_LEN;
#pragma unroll
        for (int q2 = 0; q2 < 4; ++q2) {
          const int row = row0 + 8 * q2;
          ushort4 u;
          u.x = f2bf(acc[f][g][4 * q2 + 0] + bb);
          u.y = f2bf(acc[f][g][4 * q2 + 1] + bb);
          u.z = f2bf(acc[f][g][4 * q2 + 2] + bb);
          u.w = f2bf(acc[f][g][4 * q2 + 3] + bb);
          *(ushort4*)(base + row) = u;
        }
      } else {
        u16* oq = (u16*)outbase + (size_t)z * S_LEN * DMODEL;
#pragma unroll
        for (int i = 0; i < 16; ++i) {
          const int row = row0 + (i & 3) + 8 * (i >> 2);
          oq[((size_t)(col >> 6) * S_LEN + row) * DK + (col & 63)] =
              f2bf((acc[f][g][i] + bb) * scale);
        }
      }
    }
  }
}

// ---------------------------------------------------------------------------
// Flash attention (R8 config, proven): swapped-QK^T, fixed-max base-2
// softmax, KV-split x2. 512-thread blocks (8 waves x 32 q-rows), grid 512.
// Counted-vmcnt double-barrier per tile:
//   stage(NXT) -> s_waitcnt vmcnt(2) -> s_barrier -> compute(CUR) -> s_barrier
// ---------------------------------------------------------------------------
__global__ __launch_bounds__(512) void attn2(const u16* __restrict__ q,
                                             const u16* __restrict__ k,
                                             const u16* __restrict__ vt,
                                             u16* __restrict__ Opart,
                                             float* __restrict__ Lpart) {
  __shared__ __align__(16) char smem[32768];  // 2 bufs x (K 8KB + V^T 8KB)
  const int bid0 = blockIdx.x;
  const int bid = (bid0 & 7) * 64 + (bid0 >> 3);  // XCD swizzle, 512%8==0
  const int h = bid >> 5;
  const int kvh = (bid >> 4) & 1;
  const int qblk = bid & 15;
  const int tid = threadIdx.x;
  const int wid = tid >> 6, lane = tid & 63;
  const int l31 = lane & 31, hi = lane >> 5;

  const char* kpb = (const char*)k + (size_t)h * S_LEN * (DK * 2);
  const char* vtb = (const char*)vt + (size_t)h * DK * (S_LEN * 2);

  // Q B-fragments: col=q=lane&31, kdim d = 16*dt + 8*hi + j
  const int q0w = qblk * 256 + wid * 32;
  const u16* qrow = q + ((size_t)h * S_LEN + q0w + l31) * DK;
  bf16x8 qf[4];
#pragma unroll
  for (int dt = 0; dt < 4; ++dt)
    qf[dt] = *(const bf16x8*)(qrow + dt * 16 + hi * 8);

  f32x16 o0 = {}, o1 = {};   // O^T[d,q]: o0 = d 0..31, o1 = d 32..63
  f32x2 lacc2 = {0.f, 0.f};

  const int woff = wid << 10;     // each wave stages a contiguous 1KB chunk
  const int kt0 = kvh * 32;       // 32 tiles per half
  const int kt1 = kt0 + 32;

  // loop-invariant per-lane ds-read byte offsets (swizzled)
  const int swz = (l31 & 7) << 4;
  int dsa[4];
#pragma unroll
  for (int dt = 0; dt < 4; ++dt)
    dsa[dt] = (l31 << 7) + ((dt * 32 + hi * 16) ^ swz);

  // induction global staging pointers (1 K-load + 1 V-load per thread)
  const int lin = tid * 16;                       // 0..8176, covers 8KB
  const int sw = lin ^ (((lin >> 7) & 7) << 4);
  const char* gk = kpb + (size_t)kt0 * 8192 + sw;
  const char* gv = vtb + (size_t)(lin >> 7) * 8192 + (size_t)kt0 * 128 + (sw & 127);

  // prologue: stage tile kt0 into buf0
  gload16(gk, smem + woff);          gk += 8192;
  gload16(gv, smem + 8192 + woff);   gv += 128;

  auto body = [&](const int CUR, const int NXT, bool doStage) {
    if (doStage) {
      gload16(gk, smem + NXT + woff);          gk += 8192;
      gload16(gv, smem + NXT + 8192 + woff);   gv += 128;
      asm volatile("s_waitcnt vmcnt(2)" ::: "memory");  // CUR staged; NXT in flight
    } else {
      asm volatile("s_waitcnt vmcnt(0)" ::: "memory");
    }
    __builtin_amdgcn_s_barrier();   // all waves: CUR data ready

    const char* kb = smem + CUR;
    const char* vb = smem + CUR + 8192;

    // QK^T swapped: st[k,q], A=K (row=key), B=Q (col=q)
    f32x16 st0 = {}, st1 = {};
    __builtin_amdgcn_s_setprio(1);
#pragma unroll
    for (int dt = 0; dt < 4; ++dt) {
      bf16x8 k0 = *(const bf16x8*)(kb + dsa[dt]);
      bf16x8 k1 = *(const bf16x8*)(kb + 4096 + dsa[dt]);
      st0 = __builtin_amdgcn_mfma_f32_32x32x16_bf16(k0, qf[dt], st0, 0, 0, 0);
      st1 = __builtin_amdgcn_mfma_f32_32x32x16_bf16(k1, qf[dt], st1, 0, 0, 0);
    }
    __builtin_amdgcn_s_setprio(0);

    // fixed-max base-2 softmax fused with bf16 pack: w[i]=pk(exp2,exp2)
    unsigned w0[8], w1[8];
    f32x2 s2 = {0.f, 0.f};
#pragma unroll
    for (int i = 0; i < 8; ++i) {
      float a0 = EXP2F(st0[2 * i]), a1 = EXP2F(st0[2 * i + 1]);
      f32x2 t = {a0, a1}; s2 += t;
      w0[i] = pkbf(a0, a1);
    }
#pragma unroll
    for (int i = 0; i < 8; ++i) {
      float a0 = EXP2F(st1[2 * i]), a1 = EXP2F(st1[2 * i + 1]);
      f32x2 t = {a0, a1}; s2 += t;
      w1[i] = pkbf(a0, a1);
    }
    lacc2 += s2;

    // P^T fragments: permlane32_swap pairs (w[i], w[i+2])
    union UF { unsigned w[4]; bf16x8 v; };
    UF f[4];
#pragma unroll
    for (int g = 0; g < 2; ++g) {
#pragma unroll
      for (int j = 0; j < 2; ++j) {
        unsigned a = w0[4 * g + j], b = w0[4 * g + j + 2];
        plswap(a, b, hi);
        f[g].w[j] = a; f[g].w[j + 2] = b;
        unsigned c = w1[4 * g + j], d = w1[4 * g + j + 2];
        plswap(c, d, hi);
        f[2 + g].w[j] = c; f[2 + g].w[j + 2] = d;
      }
    }

    // PV: O^T[d,q] += V^T[d,k] P^T[k,q]
    __builtin_amdgcn_s_setprio(1);
#pragma unroll
    for (int kt2 = 0; kt2 < 4; ++kt2) {
      bf16x8 v0 = *(const bf16x8*)(vb + dsa[kt2]);
      bf16x8 v1 = *(const bf16x8*)(vb + 4096 + dsa[kt2]);
      o0 = __builtin_amdgcn_mfma_f32_32x32x16_bf16(v0, f[kt2].v, o0, 0, 0, 0);
      o1 = __builtin_amdgcn_mfma_f32_32x32x16_bf16(v1, f[kt2].v, o1, 0, 0, 0);
    }
    __builtin_amdgcn_s_setprio(0);

    __builtin_amdgcn_s_barrier();   // all waves done reading CUR
  };

  for (int kt = kt0; kt < kt1; kt += 2) {
    body(0, 16384, kt + 1 < kt1);
    body(16384, 0, kt + 2 < kt1);
  }

  // epilogue: store unnormalized partial O^T (bf16) + partial l (f32)
  const float lacc = lacc2.x + lacc2.y;
  const float lrow = lacc + __shfl_xor(lacc, 32);
  u16* Ob = Opart + ((((size_t)kvh * NH + h) * S_LEN) + q0w + l31) * DK;
#pragma unroll
  for (int g = 0; g < 4; ++g) {
    ushort4 u0, u1;
    u0.x = f2bf(o0[g * 4 + 0]); u0.y = f2bf(o0[g * 4 + 1]);
    u0.z = f2bf(o0[g * 4 + 2]); u0.w = f2bf(o0[g * 4 + 3]);
    *(ushort4*)(Ob + 8 * g + 4 * hi) = u0;
    u1.x = f2bf(o1[g * 4 + 0]); u1.y = f2bf(o1[g * 4 + 1]);
    u1.z = f2bf(o1[g * 4 + 2]); u1.w = f2bf(o1[g * 4 + 3]);
    *(ushort4*)(Ob + 32 + 8 * g + 4 * hi) = u1;
  }
  Lpart[((size_t)kvh * NH + h) * S_LEN + q0w + l31] = lrow;
}

// ---------------------------------------------------------------------------
// combine: comb[q][h*64+d] = sum_kv(O_kv) / sum_kv(l_kv), bf16 partials (x2)
// ---------------------------------------------------------------------------
__global__ __launch_bounds__(256) void combine(const u16* __restrict__ Op,
                                               const float* __restrict__ Lp,
                                               u16* __restrict__ comb) {
  const int id = blockIdx.x * 256 + threadIdx.x;   // 1M threads
  const int h = id >> 16;
  const int rem = id & 65535;
  const int qv = rem >> 4;
  const int d4 = (rem & 15) << 2;
  const size_t str = (size_t)NH * S_LEN * DK;
  const size_t base = (((size_t)h * S_LEN) + qv) * DK + d4;
  float o0 = 0.f, o1 = 0.f, o2 = 0.f, o3 = 0.f, l = 0.f;
#pragma unroll
  for (int kv = 0; kv < 2; ++kv) {
    ushort4 u = *(const ushort4*)(Op + kv * str + base);
    o0 += bf2f(u.x); o1 += bf2f(u.y); o2 += bf2f(u.z); o3 += bf2f(u.w);
    l += Lp[(size_t)kv * NH * S_LEN + (size_t)h * S_LEN + qv];
  }
  const float inv = 1.f / l;
  ushort4 u;
  u.x = f2bf(o0 * inv);
  u.y = f2bf(o1 * inv);
  u.z = f2bf(o2 * inv);
  u.w = f2bf(o3 * inv);
  *(ushort4*)(comb + (size_t)qv * DMODEL + h * DK + d4) = u;
}

// ---------------------------------------------------------------------------
extern "C" void kernel_launch(void* const* d_in, const int* in_sizes, int n_in,
                              void* d_out, int out_size, void* d_ws, size_t ws_size,
                              hipStream_t stream) {
  (void)in_sizes; (void)n_in; (void)out_size; (void)ws_size;
  const float* Q   = (const float*)d_in[0];
  const float* K   = (const float*)d_in[1];
  const float* V   = (const float*)d_in[2];
  const float* W_Q = (const float*)d_in[3];
  const float* b_Q = (const float*)d_in[4];
  const float* W_K = (const float*)d_in[5];
  const float* b_K = (const float*)d_in[6];
  const float* W_V = (const float*)d_in[7];
  const float* b_V = (const float*)d_in[8];
  const float* W_O = (const float*)d_in[9];
  const float* b_O = (const float*)d_in[10];
  float* out = (float*)d_out;

  char* ws = (char*)d_ws;
  const size_t MB = 1024 * 1024;
  u16* WtQ = (u16*)ws;                        // 4 x 2MB = [0, 8MB)
  u16* Qbf = (u16*)(ws + 8 * MB);             // 3 x 8MB = [8, 32MB); dead after pgemm<0>
  u16* Opart = (u16*)(ws + 8 * MB);           // 2 x 8MB = [8, 24MB) bf16 (overlays Qbf)
  u16* qp   = (u16*)(ws + 40 * MB);           // (H,S,64)  [40,48)
  u16* kp   = qp + (size_t)S_LEN * DMODEL;    //           [48,56)
  u16* vtp  = kp + (size_t)S_LEN * DMODEL;    // (H,64,S)  [56,64)
  u16* comb = vtp + (size_t)S_LEN * DMODEL;   // (S,1024)  [64,72)
  float* Lpart = (float*)(ws + 72 * MB);      // 2 x (H,S) f32 = 512KB

  prep<<<7168, 256, 0, stream>>>(W_Q, W_K, W_V, W_O, WtQ, Q, K, V, Qbf);

  pgemm<0><<<768, 256, 0, stream>>>(Qbf, WtQ, b_Q, b_K, b_V, qp);

  attn2<<<512, 512, 0, stream>>>(qp, kp, vtp, Opart, Lpart);
  combine<<<4096, 256, 0, stream>>>(Opart, Lpart, comb);

  pgemm<1><<<256, 256, 0, stream>>>(comb, WtQ + (size_t)3 * DMODEL * DMODEL,
                                    b_O, b_O, b_O, out);
}

// Round 13
// 161.777 us; speedup vs baseline: 1.1666x; 1.0161x over previous
//
#include <hip/hip_runtime.h>

typedef float f32x2 __attribute__((ext_vector_type(2)));
typedef float f32x4 __attribute__((ext_vector_type(4)));
typedef float f32x16 __attribute__((ext_vector_type(16)));
typedef short bf16x8 __attribute__((ext_vector_type(8)));
typedef unsigned u32x2 __attribute__((ext_vector_type(2)));
typedef unsigned short u16;

#define S_LEN 4096
#define DMODEL 1024
#define NH 16
#define DK 64

// 1/sqrt(64) * log2(e): softmax runs in base-2 domain
#define SCALE_Q 0.18033688f

static __device__ __forceinline__ u16 f2bf(float x) {
  union { float f; unsigned u; } v; v.f = x;
  unsigned r = v.u + 0x7fffu + ((v.u >> 16) & 1u);  // RNE
  return (u16)(r >> 16);
}

static __device__ __forceinline__ float bf2f(u16 x) {
  union { unsigned u; float f; } v; v.u = ((unsigned)x) << 16;
  return v.f;
}

#if __has_builtin(__builtin_amdgcn_exp2f)
#define EXP2F __builtin_amdgcn_exp2f
#else
#define EXP2F exp2f
#endif

static __device__ __forceinline__ unsigned pkbf(float lo, float hi) {
  unsigned r;
  asm("v_cvt_pk_bf16_f32 %0, %1, %2" : "=v"(r) : "v"(lo), "v"(hi));
  return r;
}

static __device__ __forceinline__ void plswap(unsigned& a, unsigned& b, int hi) {
#if __has_builtin(__builtin_amdgcn_permlane32_swap)
  u32x2 r = __builtin_amdgcn_permlane32_swap(a, b, false, false);
  a = r.x; b = r.y;
  (void)hi;
#else
  unsigned ax = __shfl_xor(a, 32), bx = __shfl_xor(b, 32);
  unsigned na = hi ? bx : a;
  unsigned nb = hi ? b : ax;
  a = na; b = nb;
#endif
}

static __device__ __forceinline__ void gload16(const void* g, void* l) {
  void* gg = (void*)g;
  __builtin_amdgcn_global_load_lds(
      (__attribute__((address_space(1))) void*)gg,
      (__attribute__((address_space(3))) void*)l, 16, 0, 0);
}

// ---------------------------------------------------------------------------
// prep: one launch. blocks [0,4096): 4x W (K,N) f32 -> Wt (N,K) bf16 (32x32
// transpose tiles). blocks [4096,7168): 3x f32 -> bf16 elementwise.
// ---------------------------------------------------------------------------
__global__ __launch_bounds__(256) void prep(const float* __restrict__ W0,
                                            const float* __restrict__ W1,
                                            const float* __restrict__ W2,
                                            const float* __restrict__ W3,
                                            u16* __restrict__ Wt,
                                            const float* __restrict__ Q,
                                            const float* __restrict__ K,
                                            const float* __restrict__ V,
                                            u16* __restrict__ Qbf) {
  __shared__ float t[32][33];
  const int b = blockIdx.x;
  const int tid = threadIdx.x;
  if (b < 4096) {
    const int z = b >> 10;
    const int rem = b & 1023;
    const float* W = (z == 0) ? W0 : (z == 1) ? W1 : (z == 2) ? W2 : W3;
    u16* dst = Wt + (size_t)z * DMODEL * DMODEL;
    const int x = tid & 31, y = tid >> 5;          // 32 x 8
    const int n0 = (rem & 31) * 32, k0 = (rem >> 5) * 32;
#pragma unroll
    for (int i = 0; i < 4; ++i)
      t[y + 8 * i][x] = W[(size_t)(k0 + y + 8 * i) * DMODEL + n0 + x];
    __syncthreads();
#pragma unroll
    for (int i = 0; i < 4; ++i)
      dst[(size_t)(n0 + y + 8 * i) * DMODEL + k0 + x] = f2bf(t[x][y + 8 * i]);
  } else {
    const int b2 = b - 4096;
    const int z = b2 >> 10;
    const int blk = b2 & 1023;
    const float* src = (z == 0) ? Q : (z == 1) ? K : V;
    u16* dst = Qbf + (size_t)z * S_LEN * DMODEL;
    const int n8 = S_LEN * DMODEL / 8;
    for (int i = blk * 256 + tid; i < n8; i += 1024 * 256) {
      float4 a = ((const float4*)src)[2 * i];
      float4 c = ((const float4*)src)[2 * i + 1];
      union { ushort4 u[2]; int4 q; } tt;
      tt.u[0].x = f2bf(a.x); tt.u[0].y = f2bf(a.y);
      tt.u[0].z = f2bf(a.z); tt.u[0].w = f2bf(a.w);
      tt.u[1].x = f2bf(c.x); tt.u[1].y = f2bf(c.y);
      tt.u[1].z = f2bf(c.z); tt.u[1].w = f2bf(c.w);
      ((int4*)dst)[i] = tt.q;
    }
  }
}

// ---------------------------------------------------------------------------
// pgemm<0>: QKV projections, m97 128x128 tile, 32x32x16 MFMAs (2x2/wave).
// grid 768: z = bid>>8 selects Q/K/V; z=0/1 -> head-split bf16 (H,S,64)
// [z=0 scaled]; z=2 -> transposed bf16 (H,64,S).
// ---------------------------------------------------------------------------
template <int MODE>
__global__ __launch_bounds__(256) void pgemm(const u16* __restrict__ Abase,
                                             const u16* __restrict__ Btbase,
                                             const float* __restrict__ bq,
                                             const float* __restrict__ bk,
                                             const float* __restrict__ bv,
                                             void* __restrict__ outbase) {
  __shared__ __align__(16) char Al[16384];   // [128][128B] linear, XOR-swizzled
  __shared__ __align__(16) char Bl[16384];
  const int nblk = gridDim.x, cpx = nblk >> 3;
  const int b0 = blockIdx.x;
  const int bid = (b0 & 7) * cpx + (b0 >> 3);   // XCD swizzle (nblk%8==0)
  const int z = (MODE == 0) ? (bid >> 8) : 0;
  const int rem = bid & 255;
  const int nb = rem & 7, mb = rem >> 3;
  const int m0 = mb * 128, n0 = nb * 128;
  const int tid = threadIdx.x, lane = tid & 63, wid = tid >> 6;
  const int l31 = lane & 31, hi = lane >> 5;
  const int wm = (wid >> 1) * 64, wn = (wid & 1) * 64;
  const char* Ab = (const char*)(Abase + (size_t)z * S_LEN * DMODEL);
  const char* Bb = (const char*)(Btbase + (size_t)z * DMODEL * DMODEL);
  const float* bias = (z == 0) ? bq : (z == 1 ? bk : bv);
  const float scale = (MODE == 0 && z == 0) ? SCALE_Q : 1.0f;

  f32x16 acc[2][2] = {};

  for (int kt = 0; kt < 16; ++kt) {
    const int kb = kt * 128;
#pragma unroll
    for (int p = 0; p < 4; ++p) {
      int lin = p * 4096 + tid * 16;
      int row = lin >> 7;
      int colg = (lin & 127) ^ ((row & 7) << 4);
      gload16(Ab + (size_t)(m0 + row) * 2048 + kb + colg,
              Al + p * 4096 + wid * 1024);
    }
#pragma unroll
    for (int p = 0; p < 4; ++p) {
      int lin = p * 4096 + tid * 16;
      int row = lin >> 7;
      int colg = (lin & 127) ^ ((row & 7) << 4);
      gload16(Bb + (size_t)(n0 + row) * 2048 + kb + colg,
              Bl + p * 4096 + wid * 1024);
    }
    __syncthreads();
#pragma unroll
    for (int ks = 0; ks < 4; ++ks) {
      bf16x8 a2[2], b2[2];
#pragma unroll
      for (int f = 0; f < 2; ++f) {
        int row = wm + f * 32 + l31;
        a2[f] = *(const bf16x8*)(Al + row * 128 +
                                 ((ks * 32 + hi * 16) ^ ((row & 7) << 4)));
      }
#pragma unroll
      for (int g = 0; g < 2; ++g) {
        int row = wn + g * 32 + l31;
        b2[g] = *(const bf16x8*)(Bl + row * 128 +
                                 ((ks * 32 + hi * 16) ^ ((row & 7) << 4)));
      }
#pragma unroll
      for (int f = 0; f < 2; ++f)
#pragma unroll
        for (int g = 0; g < 2; ++g)
          acc[f][g] =
              __builtin_amdgcn_mfma_f32_32x32x16_bf16(a2[f], b2[g], acc[f][g], 0, 0, 0);
    }
    __syncthreads();
  }

  // epilogue: 32x32 C/D layout: col = l31, row = (i&3) + 8*(i>>2) + 4*hi
#pragma unroll
  for (int f = 0; f < 2; ++f) {
#pragma unroll
    for (int g = 0; g < 2; ++g) {
      const int col = n0 + wn + g * 32 + l31;
      const int row0 = m0 + wm + f * 32 + 4 * hi;
      const float bb = bias[col];
      if (MODE == 1) {
        float* of = (float*)outbase;
#pragma unroll
        for (int i = 0; i < 16; ++i) {
          const int row = row0 + (i & 3) + 8 * (i >> 2);
          of[(size_t)row * DMODEL + col] = acc[f][g][i] + bb;
        }
      } else if (z == 2) {
        // V: (H,64,S) transposed; 4 consecutive rows (s) -> one 8B store
        u16* ov = (u16*)outbase + (size_t)2 * S_LEN * DMODEL;
        u16* base = ov + ((size_t)(col >> 6) * DK + (col & 63)) * S_LEN;
#pragma unroll
        for (int q2 = 0; q2 < 4; ++q2) {
          const int row = row0 + 8 * q2;
          ushort4 u;
          u.x = f2bf(acc[f][g][4 * q2 + 0] + bb);
          u.y = f2bf(acc[f][g][4 * q2 + 1] + bb);
          u.z = f2bf(acc[f][g][4 * q2 + 2] + bb);
          u.w = f2bf(acc[f][g][4 * q2 + 3] + bb);
          *(ushort4*)(base + row) = u;
        }
      } else {
        u16* oq = (u16*)outbase + (size_t)z * S_LEN * DMODEL;
#pragma unroll
        for (int i = 0; i < 16; ++i) {
          const int row = row0 + (i & 3) + 8 * (i >> 2);
          oq[((size_t)(col >> 6) * S_LEN + row) * DK + (col & 63)] =
              f2bf((acc[f][g][i] + bb) * scale);
        }
      }
    }
  }
}

// ---------------------------------------------------------------------------
// ogemm: out(4096,1024) f32 = comb(4096,1024)bf16 @ WtO^T + bO.
// 64x128 tile -> grid 512 = 2 blocks/CU (vs 256 = 1/CU for the 128x128
// version): co-resident block overlap hides the barrier drain.
// 4 waves 2x2, wave tile 32x64 (acc f32x16[2]), 32x32x16 MFMAs.
// ---------------------------------------------------------------------------
__global__ __launch_bounds__(256) void ogemm(const u16* __restrict__ A,
                                             const u16* __restrict__ Bt,
                                             const float* __restrict__ bias,
                                             float* __restrict__ out) {
  __shared__ __align__(16) char Al[8192];    // [64][128B]
  __shared__ __align__(16) char Bl[16384];   // [128][128B]
  const int b0 = blockIdx.x;
  const int bid = (b0 & 7) * 64 + (b0 >> 3);    // XCD swizzle, 512%8==0
  const int nb = bid & 7, mb = bid >> 3;
  const int m0 = mb * 64, n0 = nb * 128;
  const int tid = threadIdx.x, lane = tid & 63, wid = tid >> 6;
  const int l31 = lane & 31, hi = lane >> 5;
  const int wm = (wid >> 1) * 32, wn = (wid & 1) * 64;
  const char* Ab = (const char*)A;
  const char* Bb = (const char*)Bt;

  f32x16 acc[2] = {};

  for (int kt = 0; kt < 16; ++kt) {
    const int kb = kt * 128;
#pragma unroll
    for (int p = 0; p < 2; ++p) {
      int lin = p * 4096 + tid * 16;
      int row = lin >> 7;
      int colg = (lin & 127) ^ ((row & 7) << 4);
      gload16(Ab + (size_t)(m0 + row) * 2048 + kb + colg,
              Al + p * 4096 + wid * 1024);
    }
#pragma unroll
    for (int p = 0; p < 4; ++p) {
      int lin = p * 4096 + tid * 16;
      int row = lin >> 7;
      int colg = (lin & 127) ^ ((row & 7) << 4);
      gload16(Bb + (size_t)(n0 + row) * 2048 + kb + colg,
              Bl + p * 4096 + wid * 1024);
    }
    __syncthreads();
#pragma unroll
    for (int ks = 0; ks < 4; ++ks) {
      int rowA = wm + l31;
      bf16x8 a2 = *(const bf16x8*)(Al + rowA * 128 +
                                   ((ks * 32 + hi * 16) ^ ((rowA & 7) << 4)));
      bf16x8 b2[2];
#pragma unroll
      for (int g = 0; g < 2; ++g) {
        int row = wn + g * 32 + l31;
        b2[g] = *(const bf16x8*)(Bl + row * 128 +
                                 ((ks * 32 + hi * 16) ^ ((row & 7) << 4)));
      }
#pragma unroll
      for (int g = 0; g < 2; ++g)
        acc[g] = __builtin_amdgcn_mfma_f32_32x32x16_bf16(a2, b2[g], acc[g], 0, 0, 0);
    }
    __syncthreads();
  }

#pragma unroll
  for (int g = 0; g < 2; ++g) {
    const int col = n0 + wn + g * 32 + l31;
    const int row0 = m0 + wm + 4 * hi;
    const float bb = bias[col];
#pragma unroll
    for (int i = 0; i < 16; ++i) {
      const int row = row0 + (i & 3) + 8 * (i >> 2);
      out[(size_t)row * DMODEL + col] = acc[g][i] + bb;
    }
  }
}

// ---------------------------------------------------------------------------
// Flash attention (R8 structure + merged double-tile bodies): swapped-QK^T,
// fixed-max base-2 softmax, KV-split x2. 512-thread blocks (8 waves x 32
// q-rows), grid 512. Each body handles 128 keys (two 64-key sub-tiles in one
// 32KB buffer: K_a,V_a,K_b,V_b) with ONE vmcnt+barrier pair -> barrier count
// halved vs R8. Registers unchanged (st/w reused across sub-tiles).
// ---------------------------------------------------------------------------
__global__ __launch_bounds__(512) void attn2(const u16* __restrict__ q,
                                             const u16* __restrict__ k,
                                             const u16* __restrict__ vt,
                                             u16* __restrict__ Opart,
                                             float* __restrict__ Lpart) {
  __shared__ __align__(16) char smem[65536];  // 2 bufs x 32KB
  const int bid0 = blockIdx.x;
  const int bid = (bid0 & 7) * 64 + (bid0 >> 3);  // XCD swizzle, 512%8==0
  const int h = bid >> 5;
  const int kvh = (bid >> 4) & 1;
  const int qblk = bid & 15;
  const int tid = threadIdx.x;
  const int wid = tid >> 6, lane = tid & 63;
  const int l31 = lane & 31, hi = lane >> 5;

  const char* kpb = (const char*)k + (size_t)h * S_LEN * (DK * 2);
  const char* vtb = (const char*)vt + (size_t)h * DK * (S_LEN * 2);

  // Q B-fragments: col=q=lane&31, kdim d = 16*dt + 8*hi + j
  const int q0w = qblk * 256 + wid * 32;
  const u16* qrow = q + ((size_t)h * S_LEN + q0w + l31) * DK;
  bf16x8 qf[4];
#pragma unroll
  for (int dt = 0; dt < 4; ++dt)
    qf[dt] = *(const bf16x8*)(qrow + dt * 16 + hi * 8);

  f32x16 o0 = {}, o1 = {};   // O^T[d,q]: o0 = d 0..31, o1 = d 32..63
  f32x2 lacc2 = {0.f, 0.f};

  const int woff = wid << 10;     // each wave stages a contiguous 1KB chunk
  const int kt0 = kvh * 32;       // 32 tiles (of 64 keys) per half

  // loop-invariant per-lane ds-read byte offsets (swizzled), buffer-relative
  const int swz = (l31 & 7) << 4;
  int dsa[4];
#pragma unroll
  for (int dt = 0; dt < 4; ++dt)
    dsa[dt] = (l31 << 7) + ((dt * 32 + hi * 16) ^ swz);

  // induction global staging pointers (per body: 2 K-loads + 2 V-loads)
  const int lin = tid * 16;                       // 0..8176, covers 8KB
  const int sw = lin ^ (((lin >> 7) & 7) << 4);
  const char* gk = kpb + (size_t)kt0 * 8192 + sw;
  const char* gv = vtb + (size_t)(lin >> 7) * 8192 + (size_t)kt0 * 128 + (sw & 127);

  // prologue: stage body0 (tiles kt0, kt0+1) into buf0
  gload16(gk, smem + woff);           gk += 8192;
  gload16(gv, smem + 8192 + woff);    gv += 128;
  gload16(gk, smem + 16384 + woff);   gk += 8192;
  gload16(gv, smem + 24576 + woff);   gv += 128;

  union UF { unsigned w[4]; bf16x8 v; };

  // one 64-key sub-tile: QK -> SM(+pack) -> PV
  auto subtile = [&](const char* kb, const char* vb) {
    f32x16 st0 = {}, st1 = {};
    __builtin_amdgcn_s_setprio(1);
#pragma unroll
    for (int dt = 0; dt < 4; ++dt) {
      bf16x8 k0 = *(const bf16x8*)(kb + dsa[dt]);
      bf16x8 k1 = *(const bf16x8*)(kb + 4096 + dsa[dt]);
      st0 = __builtin_amdgcn_mfma_f32_32x32x16_bf16(k0, qf[dt], st0, 0, 0, 0);
      st1 = __builtin_amdgcn_mfma_f32_32x32x16_bf16(k1, qf[dt], st1, 0, 0, 0);
    }
    __builtin_amdgcn_s_setprio(0);

    unsigned w0[8], w1[8];
    f32x2 s2 = {0.f, 0.f};
#pragma unroll
    for (int i = 0; i < 8; ++i) {
      float a0 = EXP2F(st0[2 * i]), a1 = EXP2F(st0[2 * i + 1]);
      f32x2 t = {a0, a1}; s2 += t;
      w0[i] = pkbf(a0, a1);
    }
#pragma unroll
    for (int i = 0; i < 8; ++i) {
      float a0 = EXP2F(st1[2 * i]), a1 = EXP2F(st1[2 * i + 1]);
      f32x2 t = {a0, a1}; s2 += t;
      w1[i] = pkbf(a0, a1);
    }
    lacc2 += s2;

    UF f[4];
#pragma unroll
    for (int g = 0; g < 2; ++g) {
#pragma unroll
      for (int j = 0; j < 2; ++j) {
        unsigned a = w0[4 * g + j], b = w0[4 * g + j + 2];
        plswap(a, b, hi);
        f[g].w[j] = a; f[g].w[j + 2] = b;
        unsigned c = w1[4 * g + j], d = w1[4 * g + j + 2];
        plswap(c, d, hi);
        f[2 + g].w[j] = c; f[2 + g].w[j + 2] = d;
      }
    }

    __builtin_amdgcn_s_setprio(1);
#pragma unroll
    for (int kt2 = 0; kt2 < 4; ++kt2) {
      bf16x8 v0 = *(const bf16x8*)(vb + dsa[kt2]);
      bf16x8 v1 = *(const bf16x8*)(vb + 4096 + dsa[kt2]);
      o0 = __builtin_amdgcn_mfma_f32_32x32x16_bf16(v0, f[kt2].v, o0, 0, 0, 0);
      o1 = __builtin_amdgcn_mfma_f32_32x32x16_bf16(v1, f[kt2].v, o1, 0, 0, 0);
    }
    __builtin_amdgcn_s_setprio(0);
  };

  auto body = [&](const int CUR, const int NXT, bool doStage) {
    if (doStage) {
      gload16(gk, smem + NXT + woff);           gk += 8192;
      gload16(gv, smem + NXT + 8192 + woff);    gv += 128;
      gload16(gk, smem + NXT + 16384 + woff);   gk += 8192;
      gload16(gv, smem + NXT + 24576 + woff);   gv += 128;
      asm volatile("s_waitcnt vmcnt(4)" ::: "memory");  // CUR's 4 complete
    } else {
      asm volatile("s_waitcnt vmcnt(0)" ::: "memory");
    }
    __builtin_amdgcn_s_barrier();   // all waves: CUR data ready

    subtile(smem + CUR, smem + CUR + 8192);             // sub-tile a
    subtile(smem + CUR + 16384, smem + CUR + 24576);    // sub-tile b

    __builtin_amdgcn_s_barrier();   // all waves done reading CUR
  };

  for (int b2 = 0; b2 < 16; b2 += 2) {     // 16 bodies = 32 tiles
    body(0, 32768, b2 + 1 < 16);
    body(32768, 0, b2 + 2 < 16);
  }

  // epilogue: store unnormalized partial O^T (bf16) + partial l (f32)
  const float lacc = lacc2.x + lacc2.y;
  const float lrow = lacc + __shfl_xor(lacc, 32);
  u16* Ob = Opart + ((((size_t)kvh * NH + h) * S_LEN) + q0w + l31) * DK;
#pragma unroll
  for (int g = 0; g < 4; ++g) {
    ushort4 u0, u1;
    u0.x = f2bf(o0[g * 4 + 0]); u0.y = f2bf(o0[g * 4 + 1]);
    u0.z = f2bf(o0[g * 4 + 2]); u0.w = f2bf(o0[g * 4 + 3]);
    *(ushort4*)(Ob + 8 * g + 4 * hi) = u0;
    u1.x = f2bf(o1[g * 4 + 0]); u1.y = f2bf(o1[g * 4 + 1]);
    u1.z = f2bf(o1[g * 4 + 2]); u1.w = f2bf(o1[g * 4 + 3]);
    *(ushort4*)(Ob + 32 + 8 * g + 4 * hi) = u1;
  }
  Lpart[((size_t)kvh * NH + h) * S_LEN + q0w + l31] = lrow;
}

// ---------------------------------------------------------------------------
// combine: comb[q][h*64+d] = sum_kv(O_kv) / sum_kv(l_kv), bf16 partials (x2)
// ---------------------------------------------------------------------------
__global__ __launch_bounds__(256) void combine(const u16* __restrict__ Op,
                                               const float* __restrict__ Lp,
                                               u16* __restrict__ comb) {
  const int id = blockIdx.x * 256 + threadIdx.x;   // 1M threads
  const int h = id >> 16;
  const int rem = id & 65535;
  const int qv = rem >> 4;
  const int d4 = (rem & 15) << 2;
  const size_t str = (size_t)NH * S_LEN * DK;
  const size_t base = (((size_t)h * S_LEN) + qv) * DK + d4;
  float o0 = 0.f, o1 = 0.f, o2 = 0.f, o3 = 0.f, l = 0.f;
#pragma unroll
  for (int kv = 0; kv < 2; ++kv) {
    ushort4 u = *(const ushort4*)(Op + kv * str + base);
    o0 += bf2f(u.x); o1 += bf2f(u.y); o2 += bf2f(u.z); o3 += bf2f(u.w);
    l += Lp[(size_t)kv * NH * S_LEN + (size_t)h * S_LEN + qv];
  }
  const float inv = 1.f / l;
  ushort4 u;
  u.x = f2bf(o0 * inv);
  u.y = f2bf(o1 * inv);
  u.z = f2bf(o2 * inv);
  u.w = f2bf(o3 * inv);
  *(ushort4*)(comb + (size_t)qv * DMODEL + h * DK + d4) = u;
}

// ---------------------------------------------------------------------------
extern "C" void kernel_launch(void* const* d_in, const int* in_sizes, int n_in,
                              void* d_out, int out_size, void* d_ws, size_t ws_size,
                              hipStream_t stream) {
  (void)in_sizes; (void)n_in; (void)out_size; (void)ws_size;
  const float* Q   = (const float*)d_in[0];
  const float* K   = (const float*)d_in[1];
  const float* V   = (const float*)d_in[2];
  const float* W_Q = (const float*)d_in[3];
  const float* b_Q = (const float*)d_in[4];
  const float* W_K = (const float*)d_in[5];
  const float* b_K = (const float*)d_in[6];
  const float* W_V = (const float*)d_in[7];
  const float* b_V = (const float*)d_in[8];
  const float* W_O = (const float*)d_in[9];
  const float* b_O = (const float*)d_in[10];
  float* out = (float*)d_out;

  char* ws = (char*)d_ws;
  const size_t MB = 1024 * 1024;
  u16* WtQ = (u16*)ws;                        // 4 x 2MB = [0, 8MB)
  u16* Qbf = (u16*)(ws + 8 * MB);             // 3 x 8MB = [8, 32MB); dead after pgemm<0>
  u16* Opart = (u16*)(ws + 8 * MB);           // 2 x 8MB = [8, 24MB) bf16 (overlays Qbf)
  u16* qp   = (u16*)(ws + 40 * MB);           // (H,S,64)  [40,48)
  u16* kp   = qp + (size_t)S_LEN * DMODEL;    //           [48,56)
  u16* vtp  = kp + (size_t)S_LEN * DMODEL;    // (H,64,S)  [56,64)
  u16* comb = vtp + (size_t)S_LEN * DMODEL;   // (S,1024)  [64,72)
  float* Lpart = (float*)(ws + 72 * MB);      // 2 x (H,S) f32 = 512KB

  prep<<<7168, 256, 0, stream>>>(W_Q, W_K, W_V, W_O, WtQ, Q, K, V, Qbf);

  pgemm<0><<<768, 256, 0, stream>>>(Qbf, WtQ, b_Q, b_K, b_V, qp);

  attn2<<<512, 512, 0, stream>>>(qp, kp, vtp, Opart, Lpart);
  combine<<<4096, 256, 0, stream>>>(Opart, Lpart, comb);

  ogemm<<<512, 256, 0, stream>>>(comb, WtQ + (size_t)3 * DMODEL * DMODEL,
                                 b_O, out);
}

// Round 15
// 154.282 us; speedup vs baseline: 1.2233x; 1.0486x over previous
//
#include <hip/hip_runtime.h>

typedef float f32x2 __attribute__((ext_vector_type(2)));
typedef float f32x4 __attribute__((ext_vector_type(4)));
typedef float f32x16 __attribute__((ext_vector_type(16)));
typedef short bf16x8 __attribute__((ext_vector_type(8)));
typedef unsigned u32x2 __attribute__((ext_vector_type(2)));
typedef unsigned short u16;

#define S_LEN 4096
#define DMODEL 1024
#define NH 16
#define DK 64

// 1/sqrt(64) * log2(e): softmax runs in base-2 domain
#define SCALE_Q 0.18033688f

static __device__ __forceinline__ u16 f2bf(float x) {
  union { float f; unsigned u; } v; v.f = x;
  unsigned r = v.u + 0x7fffu + ((v.u >> 16) & 1u);  // RNE
  return (u16)(r >> 16);
}

static __device__ __forceinline__ float bf2f(u16 x) {
  union { unsigned u; float f; } v; v.u = ((unsigned)x) << 16;
  return v.f;
}

#if __has_builtin(__builtin_amdgcn_exp2f)
#define EXP2F __builtin_amdgcn_exp2f
#else
#define EXP2F exp2f
#endif

static __device__ __forceinline__ unsigned pkbf(float lo, float hi) {
  unsigned r;
  asm("v_cvt_pk_bf16_f32 %0, %1, %2" : "=v"(r) : "v"(lo), "v"(hi));
  return r;
}

static __device__ __forceinline__ void plswap(unsigned& a, unsigned& b, int hi) {
#if __has_builtin(__builtin_amdgcn_permlane32_swap)
  u32x2 r = __builtin_amdgcn_permlane32_swap(a, b, false, false);
  a = r.x; b = r.y;
  (void)hi;
#else
  unsigned ax = __shfl_xor(a, 32), bx = __shfl_xor(b, 32);
  unsigned na = hi ? bx : a;
  unsigned nb = hi ? b : ax;
  a = na; b = nb;
#endif
}

static __device__ __forceinline__ void gload16(const void* g, void* l) {
  void* gg = (void*)g;
  __builtin_amdgcn_global_load_lds(
      (__attribute__((address_space(1))) void*)gg,
      (__attribute__((address_space(3))) void*)l, 16, 0, 0);
}

// ---------------------------------------------------------------------------
// prep: one launch. blocks [0,4096): 4x W (K,N) f32 -> Wt (N,K) bf16 (32x32
// transpose tiles). blocks [4096,7168): 3x f32 -> bf16 elementwise.
// ---------------------------------------------------------------------------
__global__ __launch_bounds__(256) void prep(const float* __restrict__ W0,
                                            const float* __restrict__ W1,
                                            const float* __restrict__ W2,
                                            const float* __restrict__ W3,
                                            u16* __restrict__ Wt,
                                            const float* __restrict__ Q,
                                            const float* __restrict__ K,
                                            const float* __restrict__ V,
                                            u16* __restrict__ Qbf) {
  __shared__ float t[32][33];
  const int b = blockIdx.x;
  const int tid = threadIdx.x;
  if (b < 4096) {
    const int z = b >> 10;
    const int rem = b & 1023;
    const float* W = (z == 0) ? W0 : (z == 1) ? W1 : (z == 2) ? W2 : W3;
    u16* dst = Wt + (size_t)z * DMODEL * DMODEL;
    const int x = tid & 31, y = tid >> 5;          // 32 x 8
    const int n0 = (rem & 31) * 32, k0 = (rem >> 5) * 32;
#pragma unroll
    for (int i = 0; i < 4; ++i)
      t[y + 8 * i][x] = W[(size_t)(k0 + y + 8 * i) * DMODEL + n0 + x];
    __syncthreads();
#pragma unroll
    for (int i = 0; i < 4; ++i)
      dst[(size_t)(n0 + y + 8 * i) * DMODEL + k0 + x] = f2bf(t[x][y + 8 * i]);
  } else {
    const int b2 = b - 4096;
    const int z = b2 >> 10;
    const int blk = b2 & 1023;
    const float* src = (z == 0) ? Q : (z == 1) ? K : V;
    u16* dst = Qbf + (size_t)z * S_LEN * DMODEL;
    const int n8 = S_LEN * DMODEL / 8;
    for (int i = blk * 256 + tid; i < n8; i += 1024 * 256) {
      float4 a = ((const float4*)src)[2 * i];
      float4 c = ((const float4*)src)[2 * i + 1];
      union { ushort4 u[2]; int4 q; } tt;
      tt.u[0].x = f2bf(a.x); tt.u[0].y = f2bf(a.y);
      tt.u[0].z = f2bf(a.z); tt.u[0].w = f2bf(a.w);
      tt.u[1].x = f2bf(c.x); tt.u[1].y = f2bf(c.y);
      tt.u[1].z = f2bf(c.z); tt.u[1].w = f2bf(c.w);
      ((int4*)dst)[i] = tt.q;
    }
  }
}

// ---------------------------------------------------------------------------
// pgemm: QKV projections, 128x128 tile, BK=64 elems (128B), 32x32x16 MFMAs,
// double-buffered counted-vmcnt (attn2 skeleton). Bias PRELOADED + explicit
// vmcnt(0) drain before prologue stage so the hw vmcnt counter tracks ONLY
// staging loads (R14 lesson). K-step stride = 128 BYTES (R14 bug was 256).
// grid 768: z = bid>>8 selects Q/K/V; z=0/1 -> head-split bf16 (H,S,64)
// [z=0 scaled]; z=2 -> transposed bf16 (H,64,S). LDS 64KB -> 2 blocks/CU.
// ---------------------------------------------------------------------------
__global__ __launch_bounds__(256) void pgemm(const u16* __restrict__ Abase,
                                             const u16* __restrict__ Btbase,
                                             const float* __restrict__ bq,
                                             const float* __restrict__ bk,
                                             const float* __restrict__ bv,
                                             void* __restrict__ outbase) {
  __shared__ __align__(16) char smem[65536];  // buf: A 16KB @0, B 16KB @16384
  const int nblk = gridDim.x, cpx = nblk >> 3;
  const int b0 = blockIdx.x;
  const int bid = (b0 & 7) * cpx + (b0 >> 3);   // XCD swizzle (nblk%8==0)
  const int z = bid >> 8;
  const int rem = bid & 255;
  const int nb = rem & 7, mb = rem >> 3;
  const int m0 = mb * 128, n0 = nb * 128;
  const int tid = threadIdx.x, lane = tid & 63, wid = tid >> 6;
  const int l31 = lane & 31, hi = lane >> 5;
  const int wm = (wid >> 1) * 64, wn = (wid & 1) * 64;
  const char* Ab = (const char*)(Abase + (size_t)z * S_LEN * DMODEL);
  const char* Bb = (const char*)(Btbase + (size_t)z * DMODEL * DMODEL);
  const float* bias = (z == 0) ? bq : (z == 1 ? bk : bv);
  const float scale = (z == 0) ? SCALE_Q : 1.0f;

  f32x16 acc[2][2] = {};

  // preload bias into registers; drain vmem so counted vmcnt is exact
  float bb2[2];
#pragma unroll
  for (int g = 0; g < 2; ++g) bb2[g] = bias[n0 + wn + g * 32 + l31];
  asm volatile("s_waitcnt vmcnt(0)" ::: "memory");

  // induction staging pointers (XOR swizzle is p- and kt-invariant)
  const int r8 = tid >> 3;                               // 0..31
  const int colg = ((tid * 16) & 127) ^ ((r8 & 7) << 4);
  const char* gA = Ab + (size_t)(m0 + r8) * 2048 + colg;
  const char* gB = Bb + (size_t)(n0 + r8) * 2048 + colg;
  const int ldst = wid * 1024;

  auto stageAB = [&](int base) {
#pragma unroll
    for (int p = 0; p < 4; ++p)
      gload16(gA + p * 65536, smem + base + p * 4096 + ldst);
#pragma unroll
    for (int p = 0; p < 4; ++p)
      gload16(gB + p * 65536, smem + base + 16384 + p * 4096 + ldst);
    gA += 128; gB += 128;                      // BK = 64 elems = 128 BYTES
  };

  auto compute = [&](int base) {
    const char* Al = smem + base;
    const char* Bl = smem + base + 16384;
#pragma unroll
    for (int ks = 0; ks < 4; ++ks) {
      bf16x8 a2[2], b2[2];
#pragma unroll
      for (int f = 0; f < 2; ++f) {
        int row = wm + f * 32 + l31;
        a2[f] = *(const bf16x8*)(Al + row * 128 +
                                 ((ks * 32 + hi * 16) ^ ((row & 7) << 4)));
      }
#pragma unroll
      for (int g = 0; g < 2; ++g) {
        int row = wn + g * 32 + l31;
        b2[g] = *(const bf16x8*)(Bl + row * 128 +
                                 ((ks * 32 + hi * 16) ^ ((row & 7) << 4)));
      }
#pragma unroll
      for (int f = 0; f < 2; ++f)
#pragma unroll
        for (int g = 0; g < 2; ++g)
          acc[f][g] =
              __builtin_amdgcn_mfma_f32_32x32x16_bf16(a2[f], b2[g], acc[f][g], 0, 0, 0);
    }
  };

  auto body = [&](const int CUR, const int NXT, bool doStage) {
    __builtin_amdgcn_sched_barrier(0);          // pin stage below prior barrier
    if (doStage) {
      stageAB(NXT);
      asm volatile("s_waitcnt vmcnt(8)" ::: "memory");  // CUR's 8 complete
    } else {
      asm volatile("s_waitcnt vmcnt(0)" ::: "memory");
    }
    __builtin_amdgcn_s_barrier();
    compute(CUR);
    __builtin_amdgcn_s_barrier();
  };

  stageAB(0);                      // prologue: kt=0 -> buf0
  for (int kt = 0; kt < 16; kt += 2) {
    body(0, 32768, kt + 1 < 16);
    body(32768, 0, kt + 2 < 16);
  }

  // epilogue: 32x32 C/D layout: col = l31, row = (i&3) + 8*(i>>2) + 4*hi
#pragma unroll
  for (int f = 0; f < 2; ++f) {
#pragma unroll
    for (int g = 0; g < 2; ++g) {
      const int col = n0 + wn + g * 32 + l31;
      const int row0 = m0 + wm + f * 32 + 4 * hi;
      const float bb = bb2[g];
      if (z == 2) {
        // V: (H,64,S) transposed; 4 consecutive rows (s) -> one 8B store
        u16* ov = (u16*)outbase + (size_t)2 * S_LEN * DMODEL;
        u16* base = ov + ((size_t)(col >> 6) * DK + (col & 63)) * S_LEN;
#pragma unroll
        for (int q2 = 0; q2 < 4; ++q2) {
          const int row = row0 + 8 * q2;
          ushort4 u;
          u.x = f2bf(acc[f][g][4 * q2 + 0] + bb);
          u.y = f2bf(acc[f][g][4 * q2 + 1] + bb);
          u.z = f2bf(acc[f][g][4 * q2 + 2] + bb);
          u.w = f2bf(acc[f][g][4 * q2 + 3] + bb);
          *(ushort4*)(base + row) = u;
        }
      } else {
        u16* oq = (u16*)outbase + (size_t)z * S_LEN * DMODEL;
#pragma unroll
        for (int i = 0; i < 16; ++i) {
          const int row = row0 + (i & 3) + 8 * (i >> 2);
          oq[((size_t)(col >> 6) * S_LEN + row) * DK + (col & 63)] =
              f2bf((acc[f][g][i] + bb) * scale);
        }
      }
    }
  }
}

// ---------------------------------------------------------------------------
// ogemm: out(4096,1024) f32 = comb(4096,1024)bf16 @ WtO^T + bO.
// 64x128 tile, grid 512 = 2 blocks/CU, double-buffered (48KB) counted-vmcnt.
// Same R14 fixes: stride 128B/kt, bias preload + drain, sched_barrier guard.
// ---------------------------------------------------------------------------
__global__ __launch_bounds__(256) void ogemm(const u16* __restrict__ A,
                                             const u16* __restrict__ Bt,
                                             const float* __restrict__ bias,
                                             float* __restrict__ out) {
  __shared__ __align__(16) char smem[49152];  // buf: A 8KB @0, B 16KB @8192
  const int b0 = blockIdx.x;
  const int bid = (b0 & 7) * 64 + (b0 >> 3);    // XCD swizzle, 512%8==0
  const int nb = bid & 7, mb = bid >> 3;
  const int m0 = mb * 64, n0 = nb * 128;
  const int tid = threadIdx.x, lane = tid & 63, wid = tid >> 6;
  const int l31 = lane & 31, hi = lane >> 5;
  const int wm = (wid >> 1) * 32, wn = (wid & 1) * 64;

  f32x16 acc[2] = {};

  float bb2[2];
#pragma unroll
  for (int g = 0; g < 2; ++g) bb2[g] = bias[n0 + wn + g * 32 + l31];
  asm volatile("s_waitcnt vmcnt(0)" ::: "memory");

  const int r8 = tid >> 3;
  const int colg = ((tid * 16) & 127) ^ ((r8 & 7) << 4);
  const char* gA = (const char*)A + (size_t)(m0 + r8) * 2048 + colg;
  const char* gB = (const char*)Bt + (size_t)(n0 + r8) * 2048 + colg;
  const int ldst = wid * 1024;

  auto stageAB = [&](int base) {
#pragma unroll
    for (int p = 0; p < 2; ++p)
      gload16(gA + p * 65536, smem + base + p * 4096 + ldst);
#pragma unroll
    for (int p = 0; p < 4; ++p)
      gload16(gB + p * 65536, smem + base + 8192 + p * 4096 + ldst);
    gA += 128; gB += 128;                      // BK = 64 elems = 128 BYTES
  };

  auto compute = [&](int base) {
    const char* Al = smem + base;
    const char* Bl = smem + base + 8192;
#pragma unroll
    for (int ks = 0; ks < 4; ++ks) {
      int rowA = wm + l31;
      bf16x8 a2 = *(const bf16x8*)(Al + rowA * 128 +
                                   ((ks * 32 + hi * 16) ^ ((rowA & 7) << 4)));
      bf16x8 b2[2];
#pragma unroll
      for (int g = 0; g < 2; ++g) {
        int row = wn + g * 32 + l31;
        b2[g] = *(const bf16x8*)(Bl + row * 128 +
                                 ((ks * 32 + hi * 16) ^ ((row & 7) << 4)));
      }
#pragma unroll
      for (int g = 0; g < 2; ++g)
        acc[g] = __builtin_amdgcn_mfma_f32_32x32x16_bf16(a2, b2[g], acc[g], 0, 0, 0);
    }
  };

  auto body = [&](const int CUR, const int NXT, bool doStage) {
    __builtin_amdgcn_sched_barrier(0);
    if (doStage) {
      stageAB(NXT);
      asm volatile("s_waitcnt vmcnt(6)" ::: "memory");
    } else {
      asm volatile("s_waitcnt vmcnt(0)" ::: "memory");
    }
    __builtin_amdgcn_s_barrier();
    compute(CUR);
    __builtin_amdgcn_s_barrier();
  };

  stageAB(0);
  for (int kt = 0; kt < 16; kt += 2) {
    body(0, 24576, kt + 1 < 16);
    body(24576, 0, kt + 2 < 16);
  }

#pragma unroll
  for (int g = 0; g < 2; ++g) {
    const int col = n0 + wn + g * 32 + l31;
    const int row0 = m0 + wm + 4 * hi;
    const float bb = bb2[g];
#pragma unroll
    for (int i = 0; i < 16; ++i) {
      const int row = row0 + (i & 3) + 8 * (i >> 2);
      out[(size_t)row * DMODEL + col] = acc[g][i] + bb;
    }
  }
}

// ---------------------------------------------------------------------------
// Flash attention (R12-exact, proven 80.2us): swapped-QK^T, fixed-max base-2
// softmax, KV-split x2. 512-thread blocks (8 waves x 32 q-rows), grid 512.
// Counted-vmcnt double-barrier per 64-key tile, 32KB LDS -> 2 blocks/CU.
// ---------------------------------------------------------------------------
__global__ __launch_bounds__(512) void attn2(const u16* __restrict__ q,
                                             const u16* __restrict__ k,
                                             const u16* __restrict__ vt,
                                             u16* __restrict__ Opart,
                                             float* __restrict__ Lpart) {
  __shared__ __align__(16) char smem[32768];  // 2 bufs x (K 8KB + V^T 8KB)
  const int bid0 = blockIdx.x;
  const int bid = (bid0 & 7) * 64 + (bid0 >> 3);  // XCD swizzle, 512%8==0
  const int h = bid >> 5;
  const int kvh = (bid >> 4) & 1;
  const int qblk = bid & 15;
  const int tid = threadIdx.x;
  const int wid = tid >> 6, lane = tid & 63;
  const int l31 = lane & 31, hi = lane >> 5;

  const char* kpb = (const char*)k + (size_t)h * S_LEN * (DK * 2);
  const char* vtb = (const char*)vt + (size_t)h * DK * (S_LEN * 2);

  // Q B-fragments: col=q=lane&31, kdim d = 16*dt + 8*hi + j
  const int q0w = qblk * 256 + wid * 32;
  const u16* qrow = q + ((size_t)h * S_LEN + q0w + l31) * DK;
  bf16x8 qf[4];
#pragma unroll
  for (int dt = 0; dt < 4; ++dt)
    qf[dt] = *(const bf16x8*)(qrow + dt * 16 + hi * 8);

  f32x16 o0 = {}, o1 = {};   // O^T[d,q]: o0 = d 0..31, o1 = d 32..63
  f32x2 lacc2 = {0.f, 0.f};

  const int woff = wid << 10;     // each wave stages a contiguous 1KB chunk
  const int kt0 = kvh * 32;       // 32 tiles per half
  const int kt1 = kt0 + 32;

  // loop-invariant per-lane ds-read byte offsets (swizzled)
  const int swz = (l31 & 7) << 4;
  int dsa[4];
#pragma unroll
  for (int dt = 0; dt < 4; ++dt)
    dsa[dt] = (l31 << 7) + ((dt * 32 + hi * 16) ^ swz);

  // induction global staging pointers (1 K-load + 1 V-load per thread)
  const int lin = tid * 16;                       // 0..8176, covers 8KB
  const int sw = lin ^ (((lin >> 7) & 7) << 4);
  const char* gk = kpb + (size_t)kt0 * 8192 + sw;
  const char* gv = vtb + (size_t)(lin >> 7) * 8192 + (size_t)kt0 * 128 + (sw & 127);

  // prologue: stage tile kt0 into buf0
  gload16(gk, smem + woff);          gk += 8192;
  gload16(gv, smem + 8192 + woff);   gv += 128;

  auto body = [&](const int CUR, const int NXT, bool doStage) {
    if (doStage) {
      gload16(gk, smem + NXT + woff);          gk += 8192;
      gload16(gv, smem + NXT + 8192 + woff);   gv += 128;
      asm volatile("s_waitcnt vmcnt(2)" ::: "memory");  // CUR staged; NXT in flight
    } else {
      asm volatile("s_waitcnt vmcnt(0)" ::: "memory");
    }
    __builtin_amdgcn_s_barrier();   // all waves: CUR data ready

    const char* kb = smem + CUR;
    const char* vb = smem + CUR + 8192;

    // QK^T swapped: st[k,q], A=K (row=key), B=Q (col=q)
    f32x16 st0 = {}, st1 = {};
    __builtin_amdgcn_s_setprio(1);
#pragma unroll
    for (int dt = 0; dt < 4; ++dt) {
      bf16x8 k0 = *(const bf16x8*)(kb + dsa[dt]);
      bf16x8 k1 = *(const bf16x8*)(kb + 4096 + dsa[dt]);
      st0 = __builtin_amdgcn_mfma_f32_32x32x16_bf16(k0, qf[dt], st0, 0, 0, 0);
      st1 = __builtin_amdgcn_mfma_f32_32x32x16_bf16(k1, qf[dt], st1, 0, 0, 0);
    }
    __builtin_amdgcn_s_setprio(0);

    // fixed-max base-2 softmax fused with bf16 pack: w[i]=pk(exp2,exp2)
    unsigned w0[8], w1[8];
    f32x2 s2 = {0.f, 0.f};
#pragma unroll
    for (int i = 0; i < 8; ++i) {
      float a0 = EXP2F(st0[2 * i]), a1 = EXP2F(st0[2 * i + 1]);
      f32x2 t = {a0, a1}; s2 += t;
      w0[i] = pkbf(a0, a1);
    }
#pragma unroll
    for (int i = 0; i < 8; ++i) {
      float a0 = EXP2F(st1[2 * i]), a1 = EXP2F(st1[2 * i + 1]);
      f32x2 t = {a0, a1}; s2 += t;
      w1[i] = pkbf(a0, a1);
    }
    lacc2 += s2;

    // P^T fragments: permlane32_swap pairs (w[i], w[i+2])
    union UF { unsigned w[4]; bf16x8 v; };
    UF f[4];
#pragma unroll
    for (int g = 0; g < 2; ++g) {
#pragma unroll
      for (int j = 0; j < 2; ++j) {
        unsigned a = w0[4 * g + j], b = w0[4 * g + j + 2];
        plswap(a, b, hi);
        f[g].w[j] = a; f[g].w[j + 2] = b;
        unsigned c = w1[4 * g + j], d = w1[4 * g + j + 2];
        plswap(c, d, hi);
        f[2 + g].w[j] = c; f[2 + g].w[j + 2] = d;
      }
    }

    // PV: O^T[d,q] += V^T[d,k] P^T[k,q]
    __builtin_amdgcn_s_setprio(1);
#pragma unroll
    for (int kt2 = 0; kt2 < 4; ++kt2) {
      bf16x8 v0 = *(const bf16x8*)(vb + dsa[kt2]);
      bf16x8 v1 = *(const bf16x8*)(vb + 4096 + dsa[kt2]);
      o0 = __builtin_amdgcn_mfma_f32_32x32x16_bf16(v0, f[kt2].v, o0, 0, 0, 0);
      o1 = __builtin_amdgcn_mfma_f32_32x32x16_bf16(v1, f[kt2].v, o1, 0, 0, 0);
    }
    __builtin_amdgcn_s_setprio(0);

    __builtin_amdgcn_s_barrier();   // all waves done reading CUR
  };

  for (int kt = kt0; kt < kt1; kt += 2) {
    body(0, 16384, kt + 1 < kt1);
    body(16384, 0, kt + 2 < kt1);
  }

  // epilogue: store unnormalized partial O^T (bf16) + partial l (f32)
  const float lacc = lacc2.x + lacc2.y;
  const float lrow = lacc + __shfl_xor(lacc, 32);
  u16* Ob = Opart + ((((size_t)kvh * NH + h) * S_LEN) + q0w + l31) * DK;
#pragma unroll
  for (int g = 0; g < 4; ++g) {
    ushort4 u0, u1;
    u0.x = f2bf(o0[g * 4 + 0]); u0.y = f2bf(o0[g * 4 + 1]);
    u0.z = f2bf(o0[g * 4 + 2]); u0.w = f2bf(o0[g * 4 + 3]);
    *(ushort4*)(Ob + 8 * g + 4 * hi) = u0;
    u1.x = f2bf(o1[g * 4 + 0]); u1.y = f2bf(o1[g * 4 + 1]);
    u1.z = f2bf(o1[g * 4 + 2]); u1.w = f2bf(o1[g * 4 + 3]);
    *(ushort4*)(Ob + 32 + 8 * g + 4 * hi) = u1;
  }
  Lpart[((size_t)kvh * NH + h) * S_LEN + q0w + l31] = lrow;
}

// ---------------------------------------------------------------------------
// combine: comb[q][h*64+d] = sum_kv(O_kv) / sum_kv(l_kv), bf16 partials (x2)
// ---------------------------------------------------------------------------
__global__ __launch_bounds__(256) void combine(const u16* __restrict__ Op,
                                               const float* __restrict__ Lp,
                                               u16* __restrict__ comb) {
  const int id = blockIdx.x * 256 + threadIdx.x;   // 1M threads
  const int h = id >> 16;
  const int rem = id & 65535;
  const int qv = rem >> 4;
  const int d4 = (rem & 15) << 2;
  const size_t str = (size_t)NH * S_LEN * DK;
  const size_t base = (((size_t)h * S_LEN) + qv) * DK + d4;
  float o0 = 0.f, o1 = 0.f, o2 = 0.f, o3 = 0.f, l = 0.f;
#pragma unroll
  for (int kv = 0; kv < 2; ++kv) {
    ushort4 u = *(const ushort4*)(Op + kv * str + base);
    o0 += bf2f(u.x); o1 += bf2f(u.y); o2 += bf2f(u.z); o3 += bf2f(u.w);
    l += Lp[(size_t)kv * NH * S_LEN + (size_t)h * S_LEN + qv];
  }
  const float inv = 1.f / l;
  ushort4 u;
  u.x = f2bf(o0 * inv);
  u.y = f2bf(o1 * inv);
  u.z = f2bf(o2 * inv);
  u.w = f2bf(o3 * inv);
  *(ushort4*)(comb + (size_t)qv * DMODEL + h * DK + d4) = u;
}

// ---------------------------------------------------------------------------
extern "C" void kernel_launch(void* const* d_in, const int* in_sizes, int n_in,
                              void* d_out, int out_size, void* d_ws, size_t ws_size,
                              hipStream_t stream) {
  (void)in_sizes; (void)n_in; (void)out_size; (void)ws_size;
  const float* Q   = (const float*)d_in[0];
  const float* K   = (const float*)d_in[1];
  const float* V   = (const float*)d_in[2];
  const float* W_Q = (const float*)d_in[3];
  const float* b_Q = (const float*)d_in[4];
  const float* W_K = (const float*)d_in[5];
  const float* b_K = (const float*)d_in[6];
  const float* W_V = (const float*)d_in[7];
  const float* b_V = (const float*)d_in[8];
  const float* W_O = (const float*)d_in[9];
  const float* b_O = (const float*)d_in[10];
  float* out = (float*)d_out;

  char* ws = (char*)d_ws;
  const size_t MB = 1024 * 1024;
  u16* WtQ = (u16*)ws;                        // 4 x 2MB = [0, 8MB)
  u16* Qbf = (u16*)(ws + 8 * MB);             // 3 x 8MB = [8, 32MB); dead after pgemm
  u16* Opart = (u16*)(ws + 8 * MB);           // 2 x 8MB = [8, 24MB) bf16 (overlays Qbf)
  u16* qp   = (u16*)(ws + 40 * MB);           // (H,S,64)  [40,48)
  u16* kp   = qp + (size_t)S_LEN * DMODEL;    //           [48,56)
  u16* vtp  = kp + (size_t)S_LEN * DMODEL;    // (H,64,S)  [56,64)
  u16* comb = vtp + (size_t)S_LEN * DMODEL;   // (S,1024)  [64,72)
  float* Lpart = (float*)(ws + 72 * MB);      // 2 x (H,S) f32 = 512KB

  prep<<<7168, 256, 0, stream>>>(W_Q, W_K, W_V, W_O, WtQ, Q, K, V, Qbf);

  pgemm<<<768, 256, 0, stream>>>(Qbf, WtQ, b_Q, b_K, b_V, qp);

  attn2<<<512, 512, 0, stream>>>(qp, kp, vtp, Opart, Lpart);
  combine<<<4096, 256, 0, stream>>>(Opart, Lpart, comb);

  ogemm<<<512, 256, 0, stream>>>(comb, WtQ + (size_t)3 * DMODEL * DMODEL,
                                 b_O, out);
}